// Round 5
// baseline (1597.131 us; speedup 1.0000x reference)
//
#include <hip/hip_runtime.h>

#define NUM_ITERS 500
#define LR_F 0.001f
#define KRYLOV 3
#define VPLANE 262144    // 4*64*1024 floats per Krylov vector
// 500 = 20 segments * 25 steps; C(25,1)=25, C(25,2)=300, C(25,3)=2300

// ---- weight prep: pad 9->12 (+transpose / +flip / +bypass slot) -------------
// grid 96 x 256 = 24576 tasks = 3 tables x 8192 (o,c) pairs
__global__ __launch_bounds__(256) void k_prep(const float* __restrict__ Wff,
                                              const float* __restrict__ Wfb,
                                              const float* __restrict__ Wb,
                                              float* __restrict__ WffP,
                                              float* __restrict__ WtF,
                                              float* __restrict__ WFlip) {
  int g = blockIdx.x * 256 + threadIdx.x;
  int table = g >> 13, t = g & 8191;
  float w[12];
#pragma unroll
  for (int k = 0; k < 12; ++k) w[k] = 0.f;
  float* dst;
  if (table == 0) {                       // WtF[o][c][12] = Wfb[(c*64+o)*9+k]
    int o = t >> 7, c = t & 127;
    const float* src = Wfb + (size_t)(c * 64 + o) * 9;
#pragma unroll
    for (int k = 0; k < 9; ++k) w[k] = src[k];
    dst = WtF + (size_t)t * 12;
  } else if (table == 1) {                // WffP[co*64+ci][12] = Wff[...*9+k]
    const float* src = Wff + (size_t)t * 9;
#pragma unroll
    for (int k = 0; k < 9; ++k) w[k] = src[k];
    dst = WffP + (size_t)t * 12;
  } else {                                // WFlip: flipped 3x3 + bypass in [9]
    const float* src = Wfb + (size_t)t * 9;
#pragma unroll
    for (int k = 0; k < 9; ++k) w[k] = src[8 - k];
    w[9] = Wb[t];
    dst = WFlip + (size_t)t * 12;
  }
  float4 v0 = {w[0], w[1], w[2], w[3]};
  float4 v1 = {w[4], w[5], w[6], w[7]};
  float4 v2 = {w[8], w[9], w[10], w[11]};
  ((float4*)dst)[0] = v0; ((float4*)dst)[1] = v1; ((float4*)dst)[2] = v2;
}

// ---- conv micro-bodies ------------------------------------------------------
// staged plane band: pitch 40, input col j at LDS col j+4 (halo zero).
// f[m] = input col c0-2+m ; 3x3 tap (di,dj) for px k needs m = k+dj+1.

__device__ __forceinline__ void conv3x2(const float* __restrict__ buf,   // 4 planes x 240
                                        const float* __restrict__ w0p,   // [ci][12]
                                        const float* __restrict__ w1p,
                                        int stci, int row_l, int c0,
                                        float a0[4], float a1[4]) {
#pragma unroll
  for (int cl = 0; cl < 4; ++cl) {
    const float* wp0 = w0p + (size_t)(stci + cl) * 12;
    const float* wp1 = w1p + (size_t)(stci + cl) * 12;
    float w0r[12], w1r[12];
    *(float4*)&w0r[0] = ((const float4*)wp0)[0];
    *(float4*)&w0r[4] = ((const float4*)wp0)[1];
    *(float4*)&w0r[8] = ((const float4*)wp0)[2];
    *(float4*)&w1r[0] = ((const float4*)wp1)[0];
    *(float4*)&w1r[4] = ((const float4*)wp1)[1];
    *(float4*)&w1r[8] = ((const float4*)wp1)[2];
    const float* pb = buf + cl * 240;
#pragma unroll
    for (int di = 0; di < 3; ++di) {
      const float* rp = pb + (row_l + di) * 40 + c0 + 2;
      float f[8];
      *(float2*)&f[0] = *(const float2*)(rp);
      *(float2*)&f[2] = *(const float2*)(rp + 2);
      *(float2*)&f[4] = *(const float2*)(rp + 4);
      *(float2*)&f[6] = *(const float2*)(rp + 6);
#pragma unroll
      for (int dj = 0; dj < 3; ++dj) {
        float wa = w0r[di * 3 + dj], wb = w1r[di * 3 + dj];
#pragma unroll
        for (int k = 0; k < 4; ++k) {
          a0[k] = fmaf(f[k + dj + 1], wa, a0[k]);
          a1[k] = fmaf(f[k + dj + 1], wb, a1[k]);
        }
      }
    }
  }
}

__device__ __forceinline__ void conv3x1(const float* __restrict__ buf,
                                        const float* __restrict__ wp_base,  // [ci][12]
                                        int stci, int row_l, int c0, float a[4]) {
#pragma unroll
  for (int cl = 0; cl < 4; ++cl) {
    const float* wp = wp_base + (size_t)(stci + cl) * 12;
    float wr[12];
    *(float4*)&wr[0] = ((const float4*)wp)[0];
    *(float4*)&wr[4] = ((const float4*)wp)[1];
    *(float4*)&wr[8] = ((const float4*)wp)[2];
    const float* pb = buf + cl * 240;
#pragma unroll
    for (int di = 0; di < 3; ++di) {
      const float* rp = pb + (row_l + di) * 40 + c0 + 2;
      float f[8];
      *(float2*)&f[0] = *(const float2*)(rp);
      *(float2*)&f[2] = *(const float2*)(rp + 2);
      *(float2*)&f[4] = *(const float2*)(rp + 4);
      *(float2*)&f[6] = *(const float2*)(rp + 6);
#pragma unroll
      for (int dj = 0; dj < 3; ++dj) {
        float wv = wr[di * 3 + dj];
#pragma unroll
        for (int k = 0; k < 4; ++k) a[k] = fmaf(f[k + dj + 1], wv, a[k]);
      }
    }
  }
}

// 5x5: f[m] = input col q0-2+m ; tap (di,dj) for px k needs m = k+dj.
__device__ __forceinline__ void conv5x1(const float* __restrict__ buf,   // 4 planes x 320
                                        const float* __restrict__ wbase, // [ci][32]
                                        int stci, int row_l, int q0,
                                        float& A0, float& A1) {
#pragma unroll
  for (int cl = 0; cl < 4; ++cl) {
    const float* wp = wbase + (size_t)(stci + cl) * 32;
    float w[28];
#pragma unroll
    for (int i = 0; i < 7; ++i) *(float4*)&w[4 * i] = ((const float4*)wp)[i];
    const float* pb = buf + cl * 320;
#pragma unroll
    for (int di = 0; di < 5; ++di) {
      const float* rp = pb + (row_l + di) * 40 + q0 + 2;
      float f[8];
      *(float2*)&f[0] = *(const float2*)(rp);
      *(float2*)&f[2] = *(const float2*)(rp + 2);
      *(float2*)&f[4] = *(const float2*)(rp + 4);
      *(float2*)&f[6] = *(const float2*)(rp + 6);
#pragma unroll
      for (int dj = 0; dj < 5; ++dj) {
        float wv = w[di * 5 + dj];
        A0 = fmaf(f[dj], wv, A0);
        A1 = fmaf(f[dj + 1], wv, A1);
      }
    }
  }
}

// ---- k_init: yp0(unpadded 32x32) = relu(conv3x3 pad1(x, Wff)) ---------------
// grid 256 = b(2) | coT(3) | band(3); block: 16 co x 4 rows x 32 cols
__global__ __launch_bounds__(256) void k_init(const float* __restrict__ x,
                                              const float* __restrict__ WffP,
                                              float* __restrict__ yp0) {
  __shared__ __align__(16) float wS[12288];   // [16 co][64 ci][12]
  __shared__ __align__(16) float sS[1920];    // [2][4 pl][6*40]
  int tid = threadIdx.x, blk = blockIdx.x;
  int b = blk >> 6, coT = (blk >> 3) & 7, band = blk & 7;
  {
    const float4* src = (const float4*)(WffP + (size_t)coT * 12288);
    float4* d4 = (float4*)wS;
    for (int i = tid; i < 3072; i += 256) d4[i] = src[i];
  }
  for (int i = tid; i < 1920; i += 256) sS[i] = 0.f;
  int wv = tid >> 6, lane = tid & 63;
  int srow = lane >> 3, scol = lane & 7;
  int gr = band * 4 - 1 + srow;
  bool sv = (srow < 6) && (gr >= 0) && (gr < 32);
  const float* sbase = x + (size_t)(b * 64 + wv) * 1024 + gr * 32 + scol * 4;
  float* sd0 = sS + wv * 240 + srow * 40 + 4 + scol * 4;
  int co2 = tid >> 5;                 // 0..7 -> co pair
  int pg = tid & 31;
  int row_l = pg >> 3, c0 = (pg & 7) * 4;
  const float* w0p = wS + (size_t)(co2 * 2) * 768;
  const float* w1p = w0p + 768;
  float a0[4] = {0, 0, 0, 0}, a1[4] = {0, 0, 0, 0};
  float4 stg;
  if (sv) stg = *(const float4*)(sbase);
  __syncthreads();
  if (sv) *(float4*)sd0 = stg;
  __syncthreads();
  for (int st = 0; st < 16; st += 2) {
    if (sv) stg = *(const float4*)(sbase + (size_t)((st + 1) * 4) * 1024);
    conv3x2(sS, w0p, w1p, st * 4, row_l, c0, a0, a1);
    if (sv) *(float4*)(sd0 + 960) = stg;
    __syncthreads();
    bool more = (st + 2 < 16);
    if (more && sv) stg = *(const float4*)(sbase + (size_t)((st + 2) * 4) * 1024);
    conv3x2(sS + 960, w0p, w1p, (st + 1) * 4, row_l, c0, a0, a1);
    if (more && sv) *(float4*)sd0 = stg;
    __syncthreads();
  }
  int gi = band * 4 + row_l;
  int co = coT * 16 + co2 * 2;
  float4 o0 = {a0[0] > 0.f ? a0[0] : 0.f, a0[1] > 0.f ? a0[1] : 0.f,
               a0[2] > 0.f ? a0[2] : 0.f, a0[3] > 0.f ? a0[3] : 0.f};
  float4 o1 = {a1[0] > 0.f ? a1[0] : 0.f, a1[1] > 0.f ? a1[1] : 0.f,
               a1[2] > 0.f ? a1[2] : 0.f, a1[3] > 0.f ? a1[3] : 0.f};
  *(float4*)(yp0 + (size_t)(b * 128 + co) * 1024 + gi * 32 + c0) = o0;
  *(float4*)(yp0 + (size_t)(b * 128 + co + 1) * 1024 + gi * 32 + c0) = o1;
}

// ---- k_gram: G[(o'*64+o)*32 + tap] (5x5 Gram of Wfb), zero pad+Gam ---------
__global__ __launch_bounds__(256) void k_gram(const float* __restrict__ Wfb,
                                              float* __restrict__ G,
                                              float* __restrict__ Gam) {
  __shared__ float wA[128 * 9];
  __shared__ float gred[256][25];
  int tid = threadIdx.x;
  int op = blockIdx.x;
  if (blockIdx.x == 0 && tid < 16) Gam[tid] = 0.f;
  for (int i = tid; i < 1152; i += 256) {
    int c = i / 9, k = i - c * 9;
    wA[i] = Wfb[(size_t)(c * 64 + op) * 9 + k];
  }
  __syncthreads();
  int o = tid & 63, part = tid >> 6;
  float g[25];
#pragma unroll
  for (int i = 0; i < 25; ++i) g[i] = 0.f;
  for (int c = part * 32; c < part * 32 + 32; ++c) {
    float b9[9];
#pragma unroll
    for (int k = 0; k < 9; ++k) b9[k] = Wfb[(size_t)(c * 64 + o) * 9 + k];
    const float* a9 = &wA[c * 9];
#pragma unroll
    for (int ei = 0; ei < 3; ++ei)
#pragma unroll
      for (int ej = 0; ej < 3; ++ej) {
        float av = a9[ei * 3 + ej];
#pragma unroll
        for (int di = 0; di < 3; ++di)
#pragma unroll
          for (int dj = 0; dj < 3; ++dj)
            g[(ei - di + 2) * 5 + (ej - dj + 2)] = fmaf(av, b9[di * 3 + dj],
                                                        g[(ei - di + 2) * 5 + (ej - dj + 2)]);
      }
  }
#pragma unroll
  for (int i = 0; i < 25; ++i) gred[tid][i] = g[i];
  __syncthreads();
  if (part == 0) {
    float* dst = G + ((size_t)op * 64 + o) * 32;
#pragma unroll
    for (int i = 0; i < 25; ++i)
      dst[i] = gred[tid][i] + gred[tid + 64][i] + gred[tid + 128][i] + gred[tid + 192][i];
#pragma unroll
    for (int i = 25; i < 32; ++i) dst[i] = 0.f;
  }
}

// ---- k_forward: v0 = x - conv3x3 pad1(yp0, WtF) -----------------------------
// grid 256 = b(2) | oT(3) | band(3); block: 8 och x 4 rows x 32 cols; 32 steps
__global__ __launch_bounds__(256) void k_forward(const float* __restrict__ x,
                                                 const float* __restrict__ WtF,
                                                 const float* __restrict__ yp0,
                                                 float* __restrict__ v0) {
  __shared__ __align__(16) float wS[12288];   // [8 och][128 ci][12]
  __shared__ __align__(16) float sS[1920];
  int tid = threadIdx.x, blk = blockIdx.x;
  int b = blk >> 6, oT = (blk >> 3) & 7, band = blk & 7;
  {
    const float4* src = (const float4*)(WtF + (size_t)oT * 12288);
    float4* d4 = (float4*)wS;
    for (int i = tid; i < 3072; i += 256) d4[i] = src[i];
  }
  for (int i = tid; i < 1920; i += 256) sS[i] = 0.f;
  int wv = tid >> 6, lane = tid & 63;
  int srow = lane >> 3, scol = lane & 7;
  int gr = band * 4 - 1 + srow;
  bool sv = (srow < 6) && (gr >= 0) && (gr < 32);
  const float* sbase = yp0 + (size_t)(b * 128 + wv) * 1024 + gr * 32 + scol * 4;
  float* sd0 = sS + wv * 240 + srow * 40 + 4 + scol * 4;
  int och_l = tid >> 5;               // 0..7
  int pg = tid & 31;
  int row_l = pg >> 3, c0 = (pg & 7) * 4;
  const float* wp_base = wS + (size_t)och_l * 1536;   // 128*12
  float acc[4] = {0, 0, 0, 0};
  float4 stg;
  if (sv) stg = *(const float4*)(sbase);
  __syncthreads();
  if (sv) *(float4*)sd0 = stg;
  __syncthreads();
  for (int st = 0; st < 32; st += 2) {
    if (sv) stg = *(const float4*)(sbase + (size_t)((st + 1) * 4) * 1024);
    conv3x1(sS, wp_base, st * 4, row_l, c0, acc);
    if (sv) *(float4*)(sd0 + 960) = stg;
    __syncthreads();
    bool more = (st + 2 < 32);
    if (more && sv) stg = *(const float4*)(sbase + (size_t)((st + 2) * 4) * 1024);
    conv3x1(sS + 960, wp_base, (st + 1) * 4, row_l, c0, acc);
    if (more && sv) *(float4*)sd0 = stg;
    __syncthreads();
  }
  int gi = band * 4 + row_l;
  int och = oT * 8 + och_l;
  size_t off = (size_t)(b * 64 + och) * 1024 + gi * 32 + c0;
  float4 xv = *(const float4*)(x + off);
  float4 rv = {xv.x - acc[0], xv.y - acc[1], xv.z - acc[2], xv.w - acc[3]};
  *(float4*)(v0 + off) = rv;
}

// ---- k_applyG: v_{j+1} = G (*) v_j (5x5 pad2, 64->64ch) ---------------------
// grid 512 = b(2) | ochT(4) | band(3); block: 4 och x 4 rows x 32 cols; 16 steps
__global__ __launch_bounds__(256, 2) void k_applyG(const float* __restrict__ vin,
                                                   float* __restrict__ vout,
                                                   const float* __restrict__ G) {
  __shared__ __align__(16) float wG[8192];    // [4 och][64 ci][32]
  __shared__ __align__(16) float sS[2560];    // [2][4 pl][8*40]
  int tid = threadIdx.x, blk = blockIdx.x;
  int b = blk >> 7, ochT = (blk >> 3) & 15, band = blk & 7;
  {
    const float4* src = (const float4*)(G + (size_t)ochT * 8192);
    float4* d4 = (float4*)wG;
    for (int i = tid; i < 2048; i += 256) d4[i] = src[i];
  }
  for (int i = tid; i < 2560; i += 256) sS[i] = 0.f;
  int wv = tid >> 6, lane = tid & 63;
  int srow = lane >> 3, scol = lane & 7;
  int gr = band * 4 - 2 + srow;
  bool sv = (gr >= 0) && (gr < 32);
  const float* sbase = vin + (size_t)(b * 64 + wv) * 1024 + gr * 32 + scol * 4;
  float* sd0 = sS + wv * 320 + srow * 40 + 4 + scol * 4;
  int och_l = __builtin_amdgcn_readfirstlane(tid >> 6);
  int row_l = (tid >> 4) & 3;
  int q0 = (tid & 15) * 2;
  const float* wbase = wG + (size_t)och_l * 2048;     // 64*32
  float A0 = 0.f, A1 = 0.f;
  float4 stg;
  if (sv) stg = *(const float4*)(sbase);
  __syncthreads();
  if (sv) *(float4*)sd0 = stg;
  __syncthreads();
  for (int st = 0; st < 16; st += 2) {
    if (sv) stg = *(const float4*)(sbase + (size_t)((st + 1) * 4) * 1024);
    conv5x1(sS, wbase, st * 4, row_l, q0, A0, A1);
    if (sv) *(float4*)(sd0 + 1280) = stg;
    __syncthreads();
    bool more = (st + 2 < 16);
    if (more && sv) stg = *(const float4*)(sbase + (size_t)((st + 2) * 4) * 1024);
    conv5x1(sS + 1280, wbase, (st + 1) * 4, row_l, q0, A0, A1);
    if (more && sv) *(float4*)sd0 = stg;
    __syncthreads();
  }
  int gi = band * 4 + row_l;
  int och = ochT * 4 + och_l;
  float2 ov = {A0, A1};
  *(float2*)(vout + (size_t)(b * 64 + och) * 1024 + gi * 32 + q0) = ov;
}

// ---- k_gamma: Gam[i][j] = <v_i, v_j>; grid 6 pairs x 8 slices ---------------
__global__ __launch_bounds__(256) void k_gamma(const float* __restrict__ V,
                                               float* __restrict__ Gam) {
  __shared__ float ws4[4];
  int tid = threadIdx.x;
  int p = blockIdx.x >> 3, slice = blockIdx.x & 7;
  int i = 0, rem = p;
  while (rem >= KRYLOV - i) { rem -= KRYLOV - i; ++i; }
  int j = i + rem;
  const float4* vi = (const float4*)(V + (size_t)i * VPLANE);
  const float4* vj = (const float4*)(V + (size_t)j * VPLANE);
  int base = slice * 8192;
  float acc = 0.f;
  for (int t = tid; t < 8192; t += 256) {
    float4 a = vi[base + t], c = vj[base + t];
    acc = fmaf(a.x, c.x, acc);
    acc = fmaf(a.y, c.y, acc);
    acc = fmaf(a.z, c.z, acc);
    acc = fmaf(a.w, c.w, acc);
  }
#pragma unroll
  for (int d = 32; d; d >>= 1) acc += __shfl_down(acc, d, 64);
  if ((tid & 63) == 0) ws4[tid >> 6] = acc;
  __syncthreads();
  if (tid == 0) {
    float tot = ws4[0] + ws4[1] + ws4[2] + ws4[3];
    atomicAdd(&Gam[i * KRYLOV + j], tot);
    if (i != j) atomicAdd(&Gam[j * KRYLOV + i], tot);
  }
}

// ---- k_scalar: 20 closed-form segments of 25 constant-alpha steps -----------
// c <- (I-aS)^25 c = c -25a Sc +300a^2 S^2c ; d += a[25c -300a Sc +2300a^2 S^2c]
__global__ __launch_bounds__(64) void k_scalar(const float* __restrict__ Gam,
                                               float* __restrict__ dvec) {
  float g00 = Gam[0], g01 = Gam[1], g02 = Gam[2];
  float g11 = Gam[4], g12 = Gam[5], g22 = Gam[8];
  float c0 = 1.f, c1 = 0.f, c2 = 0.f;
  float d0 = 0.f, d1 = 0.f, d2 = 0.f;
#pragma unroll
  for (int seg = 0; seg < 20; ++seg) {
    float pr = g00 * c0 * c0 + g11 * c1 * c1 + g22 * c2 * c2 +
               2.f * (g01 * c0 * c1 + g02 * c0 * c2 + g12 * c1 * c2);
    float a = LR_F * __builtin_amdgcn_rsqf(pr);
    float a2 = a * a, a3 = a2 * a;
    d0 += 25.f * a * c0;
    d1 += 25.f * a * c1 - 300.f * a2 * c0;
    d2 += 25.f * a * c2 - 300.f * a2 * c1 + 2300.f * a3 * c0;
    float t1 = c1 - 25.f * a * c0;
    float t2 = c2 - 25.f * a * c1 + 300.f * a2 * c0;
    c1 = t1; c2 = t2;
  }
  if (threadIdx.x == 0) { dvec[0] = d0; dvec[1] = d1; dvec[2] = d2; }
}

// ---- k_combine: s = sum_j d_j v_j (in place over v_0) -----------------------
__global__ __launch_bounds__(256) void k_combine(float* __restrict__ V,
                                                 const float* __restrict__ dvec) {
  int idx = blockIdx.x * 256 + threadIdx.x;
  float d[KRYLOV];
#pragma unroll
  for (int i = 0; i < KRYLOV; ++i) d[i] = dvec[i];
  float4 acc = {0.f, 0.f, 0.f, 0.f};
#pragma unroll
  for (int i = 0; i < KRYLOV; ++i) {
    float4 v = *(const float4*)(V + (size_t)i * VPLANE + (size_t)idx * 4);
    acc.x = fmaf(d[i], v.x, acc.x);
    acc.y = fmaf(d[i], v.y, acc.y);
    acc.z = fmaf(d[i], v.z, acc.z);
    acc.w = fmaf(d[i], v.w, acc.w);
  }
  *(float4*)(V + (size_t)idx * 4) = acc;
}

// ---- k_finalize: out = yp0 + conv3x3 pad1(s, WFlip) + 1x1(x, Wb slot9) ------
// grid 256 = b(2) | coT(3) | band(3); block: 16 co x 4 rows x 32 cols; 16 steps
__global__ __launch_bounds__(256) void k_finalize(const float* __restrict__ x,
                                                  const float* __restrict__ WFlip,
                                                  const float* __restrict__ yp0,
                                                  const float* __restrict__ s,
                                                  float* __restrict__ out) {
  __shared__ __align__(16) float wS[12288];   // [16 co][64 ci][12] (slot9=bypass)
  __shared__ __align__(16) float sS[1920];    // s-band staging
  __shared__ __align__(16) float xS[1024];    // [2][4 pl][4*32] x-band
  int tid = threadIdx.x, blk = blockIdx.x;
  int b = blk >> 6, coT = (blk >> 3) & 7, band = blk & 7;
  {
    const float4* src = (const float4*)(WFlip + (size_t)coT * 12288);
    float4* d4 = (float4*)wS;
    for (int i = tid; i < 3072; i += 256) d4[i] = src[i];
  }
  for (int i = tid; i < 1920; i += 256) sS[i] = 0.f;
  int wv = tid >> 6, lane = tid & 63;
  int srow = lane >> 3, scol = lane & 7;
  int gr = band * 4 - 1 + srow;
  bool sv = (srow < 6) && (gr >= 0) && (gr < 32);
  const float* sbase = s + (size_t)(b * 64 + wv) * 1024 + gr * 32 + scol * 4;
  float* sd0 = sS + wv * 240 + srow * 40 + 4 + scol * 4;
  // x staging: lanes 48..63, two tasks each (4 rows x 8 colgroups)
  bool xv = (lane >= 48);
  int sub = lane - 48;
  int xr0 = sub >> 3, xc0 = sub & 7;            // task sub
  int xr1 = (sub + 16) >> 3, xc1 = (sub + 16) & 7;
  const float* xbase = x + (size_t)(b * 64 + wv) * 1024 + band * 4 * 32;
  float* xd0 = xS + wv * 128;
  int co2 = tid >> 5;
  int pg = tid & 31;
  int row_l = pg >> 3, c0 = (pg & 7) * 4;
  const float* w0p = wS + (size_t)(co2 * 2) * 768;
  const float* w1p = w0p + 768;
  float a0[4] = {0, 0, 0, 0}, a1[4] = {0, 0, 0, 0};
  float4 stg, sx0, sx1;
  if (sv) stg = *(const float4*)(sbase);
  if (xv) {
    sx0 = *(const float4*)(xbase + xr0 * 32 + xc0 * 4);
    sx1 = *(const float4*)(xbase + xr1 * 32 + xc1 * 4);
  }
  __syncthreads();
  if (sv) *(float4*)sd0 = stg;
  if (xv) {
    *(float4*)(xd0 + xr0 * 32 + xc0 * 4) = sx0;
    *(float4*)(xd0 + xr1 * 32 + xc1 * 4) = sx1;
  }
  __syncthreads();
  for (int st = 0; st < 16; st += 2) {
    size_t po1 = (size_t)((st + 1) * 4) * 1024;
    if (sv) stg = *(const float4*)(sbase + po1);
    if (xv) {
      sx0 = *(const float4*)(xbase + po1 + xr0 * 32 + xc0 * 4);
      sx1 = *(const float4*)(xbase + po1 + xr1 * 32 + xc1 * 4);
    }
    // compute buf0 (channels st*4..+3): conv + bypass
    conv3x2(sS, w0p, w1p, st * 4, row_l, c0, a0, a1);
#pragma unroll
    for (int cl = 0; cl < 4; ++cl) {
      float wb0 = w0p[(size_t)(st * 4 + cl) * 12 + 9];
      float wb1 = w1p[(size_t)(st * 4 + cl) * 12 + 9];
      float4 xq = *(const float4*)(xS + cl * 128 + row_l * 32 + c0);
      float xf[4] = {xq.x, xq.y, xq.z, xq.w};
#pragma unroll
      for (int k = 0; k < 4; ++k) {
        a0[k] = fmaf(xf[k], wb0, a0[k]);
        a1[k] = fmaf(xf[k], wb1, a1[k]);
      }
    }
    if (sv) *(float4*)(sd0 + 960) = stg;
    if (xv) {
      *(float4*)(xd0 + 512 + xr0 * 32 + xc0 * 4) = sx0;
      *(float4*)(xd0 + 512 + xr1 * 32 + xc1 * 4) = sx1;
    }
    __syncthreads();
    bool more = (st + 2 < 16);
    size_t po2 = (size_t)((st + 2) * 4) * 1024;
    if (more && sv) stg = *(const float4*)(sbase + po2);
    if (more && xv) {
      sx0 = *(const float4*)(xbase + po2 + xr0 * 32 + xc0 * 4);
      sx1 = *(const float4*)(xbase + po2 + xr1 * 32 + xc1 * 4);
    }
    conv3x2(sS + 960, w0p, w1p, (st + 1) * 4, row_l, c0, a0, a1);
#pragma unroll
    for (int cl = 0; cl < 4; ++cl) {
      float wb0 = w0p[(size_t)((st + 1) * 4 + cl) * 12 + 9];
      float wb1 = w1p[(size_t)((st + 1) * 4 + cl) * 12 + 9];
      float4 xq = *(const float4*)(xS + 512 + cl * 128 + row_l * 32 + c0);
      float xf[4] = {xq.x, xq.y, xq.z, xq.w};
#pragma unroll
      for (int k = 0; k < 4; ++k) {
        a0[k] = fmaf(xf[k], wb0, a0[k]);
        a1[k] = fmaf(xf[k], wb1, a1[k]);
      }
    }
    if (more && sv) *(float4*)sd0 = stg;
    if (more && xv) {
      *(float4*)(xd0 + xr0 * 32 + xc0 * 4) = sx0;
      *(float4*)(xd0 + xr1 * 32 + xc1 * 4) = sx1;
    }
    __syncthreads();
  }
  int gi = band * 4 + row_l;
  int co = coT * 16 + co2 * 2;
  size_t off0 = (size_t)(b * 128 + co) * 1024 + gi * 32 + c0;
  size_t off1 = off0 + 1024;
  float4 y0 = *(const float4*)(yp0 + off0);
  float4 y1 = *(const float4*)(yp0 + off1);
  float4 o0 = {a0[0] + y0.x, a0[1] + y0.y, a0[2] + y0.z, a0[3] + y0.w};
  float4 o1 = {a1[0] + y1.x, a1[1] + y1.y, a1[2] + y1.z, a1[3] + y1.w};
  *(float4*)(out + off0) = o0;
  *(float4*)(out + off1) = o1;
}

// ---- launch -----------------------------------------------------------------
extern "C" void kernel_launch(void* const* d_in, const int* in_sizes, int n_in,
                              void* d_out, int out_size, void* d_ws, size_t ws_size,
                              hipStream_t stream) {
  const float* x   = (const float*)d_in[0];
  const float* Wff = (const float*)d_in[1];
  const float* Wfb = (const float*)d_in[2];
  const float* Wb  = (const float*)d_in[3];
  float* out = (float*)d_out;

  float* yp0   = (float*)d_ws;                 // 524288
  float* V     = yp0 + 524288;                 // 3 * 262144
  float* G5    = V + (size_t)KRYLOV * VPLANE;  // 131072
  float* Gam   = G5 + 131072;                  // 16
  float* dvec  = Gam + 16;                     // 16
  float* WffP  = dvec + 16;                    // 98304
  float* WtF   = WffP + 98304;                 // 98304
  float* WFlip = WtF + 98304;                  // 98304

  hipLaunchKernelGGL(k_prep,    dim3(96),  dim3(256), 0, stream, Wff, Wfb, Wb, WffP, WtF, WFlip);
  hipLaunchKernelGGL(k_init,    dim3(256), dim3(256), 0, stream, x, WffP, yp0);
  hipLaunchKernelGGL(k_gram,    dim3(64),  dim3(256), 0, stream, Wfb, G5, Gam);
  hipLaunchKernelGGL(k_forward, dim3(256), dim3(256), 0, stream, x, WtF, yp0, V);
  for (int j = 0; j + 1 < KRYLOV; ++j) {
    hipLaunchKernelGGL(k_applyG, dim3(512), dim3(256), 0, stream,
                       V + (size_t)j * VPLANE, V + (size_t)(j + 1) * VPLANE, G5);
  }
  hipLaunchKernelGGL(k_gamma,   dim3(48),  dim3(256), 0, stream, V, Gam);
  hipLaunchKernelGGL(k_scalar,  dim3(1),   dim3(64),  0, stream, Gam, dvec);
  hipLaunchKernelGGL(k_combine, dim3(256), dim3(256), 0, stream, V, dvec);
  hipLaunchKernelGGL(k_finalize, dim3(256), dim3(256), 0, stream, x, WFlip, yp0, V, out);
}

// Round 6
// 1589.263 us; speedup vs baseline: 1.0050x; 1.0050x over previous
//
#include <hip/hip_runtime.h>

#define NUM_ITERS 500
#define LR_F 0.001f
#define KRYLOV 3
#define VPLANE 262144    // 4*64*1024 floats per Krylov vector
// 500 = 20 segments * 25 steps; C(25,1)=25, C(25,2)=300, C(25,3)=2300

// ---- register-safe unpack helpers (scalar assigns keep arrays in VGPRs) -----
__device__ __forceinline__ void ldw12(const float* __restrict__ wp, float w[12]) {
  float4 q0 = ((const float4*)wp)[0];
  float4 q1 = ((const float4*)wp)[1];
  float4 q2 = ((const float4*)wp)[2];
  w[0] = q0.x; w[1] = q0.y; w[2] = q0.z; w[3] = q0.w;
  w[4] = q1.x; w[5] = q1.y; w[6] = q1.z; w[7] = q1.w;
  w[8] = q2.x; w[9] = q2.y; w[10] = q2.z; w[11] = q2.w;
}

__device__ __forceinline__ void ldrow8(const float* __restrict__ rp, float f[8]) {
  float2 p0 = *(const float2*)(rp);
  float2 p1 = *(const float2*)(rp + 2);
  float2 p2 = *(const float2*)(rp + 4);
  float2 p3 = *(const float2*)(rp + 6);
  f[0] = p0.x; f[1] = p0.y; f[2] = p1.x; f[3] = p1.y;
  f[4] = p2.x; f[5] = p2.y; f[6] = p3.x; f[7] = p3.y;
}

// ---- weight prep: pad 9->12 (+transpose / +flip / +bypass slot) -------------
// grid 96 x 256 = 24576 tasks = 3 tables x 8192 (o,c) pairs
__global__ __launch_bounds__(256) void k_prep(const float* __restrict__ Wff,
                                              const float* __restrict__ Wfb,
                                              const float* __restrict__ Wb,
                                              float* __restrict__ WffP,
                                              float* __restrict__ WtF,
                                              float* __restrict__ WFlip) {
  int g = blockIdx.x * 256 + threadIdx.x;
  int table = g >> 13, t = g & 8191;
  float w[12];
#pragma unroll
  for (int k = 0; k < 12; ++k) w[k] = 0.f;
  float* dst;
  if (table == 0) {                       // WtF[o][c][12] = Wfb[(c*64+o)*9+k]
    int o = t >> 7, c = t & 127;
    const float* src = Wfb + (size_t)(c * 64 + o) * 9;
#pragma unroll
    for (int k = 0; k < 9; ++k) w[k] = src[k];
    dst = WtF + (size_t)t * 12;
  } else if (table == 1) {                // WffP[co*64+ci][12] = Wff[...*9+k]
    const float* src = Wff + (size_t)t * 9;
#pragma unroll
    for (int k = 0; k < 9; ++k) w[k] = src[k];
    dst = WffP + (size_t)t * 12;
  } else {                                // WFlip: flipped 3x3 + bypass in [9]
    const float* src = Wfb + (size_t)t * 9;
#pragma unroll
    for (int k = 0; k < 9; ++k) w[k] = src[8 - k];
    w[9] = Wb[t];
    dst = WFlip + (size_t)t * 12;
  }
  float4 v0 = {w[0], w[1], w[2], w[3]};
  float4 v1 = {w[4], w[5], w[6], w[7]};
  float4 v2 = {w[8], w[9], w[10], w[11]};
  ((float4*)dst)[0] = v0; ((float4*)dst)[1] = v1; ((float4*)dst)[2] = v2;
}

// ---- conv micro-bodies ------------------------------------------------------
// staged plane band: pitch 40, input col j at LDS col j+4 (halo zero).
// f[m] = input col c0-2+m ; 3x3 tap (di,dj) for px k needs m = k+dj+1.

__device__ __forceinline__ void conv3x2(const float* __restrict__ buf,   // 4 planes x 240
                                        const float* __restrict__ w0p,   // [ci][12]
                                        const float* __restrict__ w1p,
                                        int stci, int row_l, int c0,
                                        float a0[4], float a1[4]) {
#pragma unroll
  for (int cl = 0; cl < 4; ++cl) {
    float w0r[12], w1r[12];
    ldw12(w0p + (size_t)(stci + cl) * 12, w0r);
    ldw12(w1p + (size_t)(stci + cl) * 12, w1r);
    const float* pb = buf + cl * 240;
#pragma unroll
    for (int di = 0; di < 3; ++di) {
      float f[8];
      ldrow8(pb + (row_l + di) * 40 + c0 + 2, f);
#pragma unroll
      for (int dj = 0; dj < 3; ++dj) {
        float wa = w0r[di * 3 + dj], wb = w1r[di * 3 + dj];
#pragma unroll
        for (int k = 0; k < 4; ++k) {
          a0[k] = fmaf(f[k + dj + 1], wa, a0[k]);
          a1[k] = fmaf(f[k + dj + 1], wb, a1[k]);
        }
      }
    }
  }
}

__device__ __forceinline__ void conv3x1(const float* __restrict__ buf,
                                        const float* __restrict__ wp_base,  // [ci][12]
                                        int stci, int row_l, int c0, float a[4]) {
#pragma unroll
  for (int cl = 0; cl < 4; ++cl) {
    float wr[12];
    ldw12(wp_base + (size_t)(stci + cl) * 12, wr);
    const float* pb = buf + cl * 240;
#pragma unroll
    for (int di = 0; di < 3; ++di) {
      float f[8];
      ldrow8(pb + (row_l + di) * 40 + c0 + 2, f);
#pragma unroll
      for (int dj = 0; dj < 3; ++dj) {
        float wv = wr[di * 3 + dj];
#pragma unroll
        for (int k = 0; k < 4; ++k) a[k] = fmaf(f[k + dj + 1], wv, a[k]);
      }
    }
  }
}

// 5x5: f[m] = input col q0-2+m ; tap (di,dj) for px k needs m = k+dj.
__device__ __forceinline__ void conv5x1(const float* __restrict__ buf,   // 4 planes x 320
                                        const float* __restrict__ wbase, // [ci][32]
                                        int stci, int row_l, int q0,
                                        float& A0, float& A1) {
#pragma unroll
  for (int cl = 0; cl < 4; ++cl) {
    const float4* wp4 = (const float4*)(wbase + (size_t)(stci + cl) * 32);
    float4 q0v = wp4[0], q1v = wp4[1], q2v = wp4[2], q3v = wp4[3];
    float4 q4v = wp4[4], q5v = wp4[5], q6v = wp4[6];
    float w[28];
    w[0] = q0v.x;  w[1] = q0v.y;  w[2] = q0v.z;  w[3] = q0v.w;
    w[4] = q1v.x;  w[5] = q1v.y;  w[6] = q1v.z;  w[7] = q1v.w;
    w[8] = q2v.x;  w[9] = q2v.y;  w[10] = q2v.z; w[11] = q2v.w;
    w[12] = q3v.x; w[13] = q3v.y; w[14] = q3v.z; w[15] = q3v.w;
    w[16] = q4v.x; w[17] = q4v.y; w[18] = q4v.z; w[19] = q4v.w;
    w[20] = q5v.x; w[21] = q5v.y; w[22] = q5v.z; w[23] = q5v.w;
    w[24] = q6v.x; w[25] = q6v.y; w[26] = q6v.z; w[27] = q6v.w;
    const float* pb = buf + cl * 320;
#pragma unroll
    for (int di = 0; di < 5; ++di) {
      float f[8];
      ldrow8(pb + (row_l + di) * 40 + q0 + 2, f);
#pragma unroll
      for (int dj = 0; dj < 5; ++dj) {
        float wv = w[di * 5 + dj];
        A0 = fmaf(f[dj], wv, A0);
        A1 = fmaf(f[dj + 1], wv, A1);
      }
    }
  }
}

// ---- k_init: yp0(unpadded 32x32) = relu(conv3x3 pad1(x, Wff)) ---------------
// grid 256 = b(2) | coT(3) | band(3); block: 16 co x 4 rows x 32 cols
__global__ __launch_bounds__(256) void k_init(const float* __restrict__ x,
                                              const float* __restrict__ WffP,
                                              float* __restrict__ yp0) {
  __shared__ __align__(16) float wS[12288];   // [16 co][64 ci][12]
  __shared__ __align__(16) float sS[1920];    // [2][4 pl][6*40]
  int tid = threadIdx.x, blk = blockIdx.x;
  int b = blk >> 6, coT = (blk >> 3) & 7, band = blk & 7;
  {
    const float4* src = (const float4*)(WffP + (size_t)coT * 12288);
    float4* d4 = (float4*)wS;
    for (int i = tid; i < 3072; i += 256) d4[i] = src[i];
  }
  for (int i = tid; i < 1920; i += 256) sS[i] = 0.f;
  int wv = tid >> 6, lane = tid & 63;
  int srow = lane >> 3, scol = lane & 7;
  int gr = band * 4 - 1 + srow;
  bool sv = (srow < 6) && (gr >= 0) && (gr < 32);
  const float* sbase = x + (size_t)(b * 64 + wv) * 1024 + gr * 32 + scol * 4;
  float* sd0 = sS + wv * 240 + srow * 40 + 4 + scol * 4;
  int co2 = tid >> 5;                 // 0..7 -> co pair
  int pg = tid & 31;
  int row_l = pg >> 3, c0 = (pg & 7) * 4;
  const float* w0p = wS + (size_t)(co2 * 2) * 768;
  const float* w1p = w0p + 768;
  float a0[4] = {0, 0, 0, 0}, a1[4] = {0, 0, 0, 0};
  float4 stg;
  if (sv) stg = *(const float4*)(sbase);
  __syncthreads();
  if (sv) *(float4*)sd0 = stg;
  __syncthreads();
  for (int st = 0; st < 16; st += 2) {
    if (sv) stg = *(const float4*)(sbase + (size_t)((st + 1) * 4) * 1024);
    conv3x2(sS, w0p, w1p, st * 4, row_l, c0, a0, a1);
    if (sv) *(float4*)(sd0 + 960) = stg;
    __syncthreads();
    bool more = (st + 2 < 16);
    if (more && sv) stg = *(const float4*)(sbase + (size_t)((st + 2) * 4) * 1024);
    conv3x2(sS + 960, w0p, w1p, (st + 1) * 4, row_l, c0, a0, a1);
    if (more && sv) *(float4*)sd0 = stg;
    __syncthreads();
  }
  int gi = band * 4 + row_l;
  int co = coT * 16 + co2 * 2;
  float4 o0 = {a0[0] > 0.f ? a0[0] : 0.f, a0[1] > 0.f ? a0[1] : 0.f,
               a0[2] > 0.f ? a0[2] : 0.f, a0[3] > 0.f ? a0[3] : 0.f};
  float4 o1 = {a1[0] > 0.f ? a1[0] : 0.f, a1[1] > 0.f ? a1[1] : 0.f,
               a1[2] > 0.f ? a1[2] : 0.f, a1[3] > 0.f ? a1[3] : 0.f};
  *(float4*)(yp0 + (size_t)(b * 128 + co) * 1024 + gi * 32 + c0) = o0;
  *(float4*)(yp0 + (size_t)(b * 128 + co + 1) * 1024 + gi * 32 + c0) = o1;
}

// ---- k_gram: G[(o'*64+o)*32 + tap] (5x5 Gram of Wfb), zero pad+Gam ---------
__global__ __launch_bounds__(256) void k_gram(const float* __restrict__ Wfb,
                                              float* __restrict__ G,
                                              float* __restrict__ Gam) {
  __shared__ float wA[128 * 9];
  __shared__ float gred[256][25];
  int tid = threadIdx.x;
  int op = blockIdx.x;
  if (blockIdx.x == 0 && tid < 16) Gam[tid] = 0.f;
  for (int i = tid; i < 1152; i += 256) {
    int c = i / 9, k = i - c * 9;
    wA[i] = Wfb[(size_t)(c * 64 + op) * 9 + k];
  }
  __syncthreads();
  int o = tid & 63, part = tid >> 6;
  float g[25];
#pragma unroll
  for (int i = 0; i < 25; ++i) g[i] = 0.f;
  for (int c = part * 32; c < part * 32 + 32; ++c) {
    float b9[9];
#pragma unroll
    for (int k = 0; k < 9; ++k) b9[k] = Wfb[(size_t)(c * 64 + o) * 9 + k];
    const float* a9 = &wA[c * 9];
#pragma unroll
    for (int ei = 0; ei < 3; ++ei)
#pragma unroll
      for (int ej = 0; ej < 3; ++ej) {
        float av = a9[ei * 3 + ej];
#pragma unroll
        for (int di = 0; di < 3; ++di)
#pragma unroll
          for (int dj = 0; dj < 3; ++dj)
            g[(ei - di + 2) * 5 + (ej - dj + 2)] = fmaf(av, b9[di * 3 + dj],
                                                        g[(ei - di + 2) * 5 + (ej - dj + 2)]);
      }
  }
#pragma unroll
  for (int i = 0; i < 25; ++i) gred[tid][i] = g[i];
  __syncthreads();
  if (part == 0) {
    float* dst = G + ((size_t)op * 64 + o) * 32;
#pragma unroll
    for (int i = 0; i < 25; ++i)
      dst[i] = gred[tid][i] + gred[tid + 64][i] + gred[tid + 128][i] + gred[tid + 192][i];
#pragma unroll
    for (int i = 25; i < 32; ++i) dst[i] = 0.f;
  }
}

// ---- k_forward: v0 = x - conv3x3 pad1(yp0, WtF) -----------------------------
// grid 256 = b(2) | oT(3) | band(3); block: 8 och x 4 rows x 32 cols; 32 steps
__global__ __launch_bounds__(256) void k_forward(const float* __restrict__ x,
                                                 const float* __restrict__ WtF,
                                                 const float* __restrict__ yp0,
                                                 float* __restrict__ v0) {
  __shared__ __align__(16) float wS[12288];   // [8 och][128 ci][12]
  __shared__ __align__(16) float sS[1920];
  int tid = threadIdx.x, blk = blockIdx.x;
  int b = blk >> 6, oT = (blk >> 3) & 7, band = blk & 7;
  {
    const float4* src = (const float4*)(WtF + (size_t)oT * 12288);
    float4* d4 = (float4*)wS;
    for (int i = tid; i < 3072; i += 256) d4[i] = src[i];
  }
  for (int i = tid; i < 1920; i += 256) sS[i] = 0.f;
  int wv = tid >> 6, lane = tid & 63;
  int srow = lane >> 3, scol = lane & 7;
  int gr = band * 4 - 1 + srow;
  bool sv = (srow < 6) && (gr >= 0) && (gr < 32);
  const float* sbase = yp0 + (size_t)(b * 128 + wv) * 1024 + gr * 32 + scol * 4;
  float* sd0 = sS + wv * 240 + srow * 40 + 4 + scol * 4;
  int och_l = tid >> 5;               // 0..7
  int pg = tid & 31;
  int row_l = pg >> 3, c0 = (pg & 7) * 4;
  const float* wp_base = wS + (size_t)och_l * 1536;   // 128*12
  float acc[4] = {0, 0, 0, 0};
  float4 stg;
  if (sv) stg = *(const float4*)(sbase);
  __syncthreads();
  if (sv) *(float4*)sd0 = stg;
  __syncthreads();
  for (int st = 0; st < 32; st += 2) {
    if (sv) stg = *(const float4*)(sbase + (size_t)((st + 1) * 4) * 1024);
    conv3x1(sS, wp_base, st * 4, row_l, c0, acc);
    if (sv) *(float4*)(sd0 + 960) = stg;
    __syncthreads();
    bool more = (st + 2 < 32);
    if (more && sv) stg = *(const float4*)(sbase + (size_t)((st + 2) * 4) * 1024);
    conv3x1(sS + 960, wp_base, (st + 1) * 4, row_l, c0, acc);
    if (more && sv) *(float4*)sd0 = stg;
    __syncthreads();
  }
  int gi = band * 4 + row_l;
  int och = oT * 8 + och_l;
  size_t off = (size_t)(b * 64 + och) * 1024 + gi * 32 + c0;
  float4 xv = *(const float4*)(x + off);
  float4 rv = {xv.x - acc[0], xv.y - acc[1], xv.z - acc[2], xv.w - acc[3]};
  *(float4*)(v0 + off) = rv;
}

// ---- k_applyG: v_{j+1} = G (*) v_j (5x5 pad2, 64->64ch) ---------------------
// grid 512 = b(2) | ochT(4) | band(3); block: 4 och x 4 rows x 32 cols; 16 steps
__global__ __launch_bounds__(256, 2) void k_applyG(const float* __restrict__ vin,
                                                   float* __restrict__ vout,
                                                   const float* __restrict__ G) {
  __shared__ __align__(16) float wG[8192];    // [4 och][64 ci][32]
  __shared__ __align__(16) float sS[2560];    // [2][4 pl][8*40]
  int tid = threadIdx.x, blk = blockIdx.x;
  int b = blk >> 7, ochT = (blk >> 3) & 15, band = blk & 7;
  {
    const float4* src = (const float4*)(G + (size_t)ochT * 8192);
    float4* d4 = (float4*)wG;
    for (int i = tid; i < 2048; i += 256) d4[i] = src[i];
  }
  for (int i = tid; i < 2560; i += 256) sS[i] = 0.f;
  int wv = tid >> 6, lane = tid & 63;
  int srow = lane >> 3, scol = lane & 7;
  int gr = band * 4 - 2 + srow;
  bool sv = (gr >= 0) && (gr < 32);
  const float* sbase = vin + (size_t)(b * 64 + wv) * 1024 + gr * 32 + scol * 4;
  float* sd0 = sS + wv * 320 + srow * 40 + 4 + scol * 4;
  int och_l = __builtin_amdgcn_readfirstlane(tid >> 6);
  int row_l = (tid >> 4) & 3;
  int q0 = (tid & 15) * 2;
  const float* wbase = wG + (size_t)och_l * 2048;     // 64*32
  float A0 = 0.f, A1 = 0.f;
  float4 stg;
  if (sv) stg = *(const float4*)(sbase);
  __syncthreads();
  if (sv) *(float4*)sd0 = stg;
  __syncthreads();
  for (int st = 0; st < 16; st += 2) {
    if (sv) stg = *(const float4*)(sbase + (size_t)((st + 1) * 4) * 1024);
    conv5x1(sS, wbase, st * 4, row_l, q0, A0, A1);
    if (sv) *(float4*)(sd0 + 1280) = stg;
    __syncthreads();
    bool more = (st + 2 < 16);
    if (more && sv) stg = *(const float4*)(sbase + (size_t)((st + 2) * 4) * 1024);
    conv5x1(sS + 1280, wbase, (st + 1) * 4, row_l, q0, A0, A1);
    if (more && sv) *(float4*)sd0 = stg;
    __syncthreads();
  }
  int gi = band * 4 + row_l;
  int och = ochT * 4 + och_l;
  float2 ov = {A0, A1};
  *(float2*)(vout + (size_t)(b * 64 + och) * 1024 + gi * 32 + q0) = ov;
}

// ---- k_gamma: Gam[i][j] = <v_i, v_j>; grid 6 pairs x 8 slices ---------------
__global__ __launch_bounds__(256) void k_gamma(const float* __restrict__ V,
                                               float* __restrict__ Gam) {
  __shared__ float ws4[4];
  int tid = threadIdx.x;
  int p = blockIdx.x >> 3, slice = blockIdx.x & 7;
  int i = 0, rem = p;
  while (rem >= KRYLOV - i) { rem -= KRYLOV - i; ++i; }
  int j = i + rem;
  const float4* vi = (const float4*)(V + (size_t)i * VPLANE);
  const float4* vj = (const float4*)(V + (size_t)j * VPLANE);
  int base = slice * 8192;
  float acc = 0.f;
  for (int t = tid; t < 8192; t += 256) {
    float4 a = vi[base + t], c = vj[base + t];
    acc = fmaf(a.x, c.x, acc);
    acc = fmaf(a.y, c.y, acc);
    acc = fmaf(a.z, c.z, acc);
    acc = fmaf(a.w, c.w, acc);
  }
#pragma unroll
  for (int d = 32; d; d >>= 1) acc += __shfl_down(acc, d, 64);
  if ((tid & 63) == 0) ws4[tid >> 6] = acc;
  __syncthreads();
  if (tid == 0) {
    float tot = ws4[0] + ws4[1] + ws4[2] + ws4[3];
    atomicAdd(&Gam[i * KRYLOV + j], tot);
    if (i != j) atomicAdd(&Gam[j * KRYLOV + i], tot);
  }
}

// ---- k_scalar: 20 closed-form segments of 25 constant-alpha steps -----------
// c <- (I-aS)^25 c = c -25a Sc +300a^2 S^2c ; d += a[25c -300a Sc +2300a^2 S^2c]
__global__ __launch_bounds__(64) void k_scalar(const float* __restrict__ Gam,
                                               float* __restrict__ dvec) {
  float g00 = Gam[0], g01 = Gam[1], g02 = Gam[2];
  float g11 = Gam[4], g12 = Gam[5], g22 = Gam[8];
  float c0 = 1.f, c1 = 0.f, c2 = 0.f;
  float d0 = 0.f, d1 = 0.f, d2 = 0.f;
#pragma unroll
  for (int seg = 0; seg < 20; ++seg) {
    float pr = g00 * c0 * c0 + g11 * c1 * c1 + g22 * c2 * c2 +
               2.f * (g01 * c0 * c1 + g02 * c0 * c2 + g12 * c1 * c2);
    float a = LR_F * __builtin_amdgcn_rsqf(pr);
    float a2 = a * a, a3 = a2 * a;
    d0 += 25.f * a * c0;
    d1 += 25.f * a * c1 - 300.f * a2 * c0;
    d2 += 25.f * a * c2 - 300.f * a2 * c1 + 2300.f * a3 * c0;
    float t1 = c1 - 25.f * a * c0;
    float t2 = c2 - 25.f * a * c1 + 300.f * a2 * c0;
    c1 = t1; c2 = t2;
  }
  if (threadIdx.x == 0) { dvec[0] = d0; dvec[1] = d1; dvec[2] = d2; }
}

// ---- k_combine: s = sum_j d_j v_j (in place over v_0) -----------------------
__global__ __launch_bounds__(256) void k_combine(float* __restrict__ V,
                                                 const float* __restrict__ dvec) {
  int idx = blockIdx.x * 256 + threadIdx.x;
  float d[KRYLOV];
#pragma unroll
  for (int i = 0; i < KRYLOV; ++i) d[i] = dvec[i];
  float4 acc = {0.f, 0.f, 0.f, 0.f};
#pragma unroll
  for (int i = 0; i < KRYLOV; ++i) {
    float4 v = *(const float4*)(V + (size_t)i * VPLANE + (size_t)idx * 4);
    acc.x = fmaf(d[i], v.x, acc.x);
    acc.y = fmaf(d[i], v.y, acc.y);
    acc.z = fmaf(d[i], v.z, acc.z);
    acc.w = fmaf(d[i], v.w, acc.w);
  }
  *(float4*)(V + (size_t)idx * 4) = acc;
}

// ---- k_finalize: out = yp0 + conv3x3 pad1(s, WFlip) + 1x1(x, Wb slot9) ------
// grid 256 = b(2) | coT(3) | band(3); block: 16 co x 4 rows x 32 cols; 16 steps
__global__ __launch_bounds__(256) void k_finalize(const float* __restrict__ x,
                                                  const float* __restrict__ WFlip,
                                                  const float* __restrict__ yp0,
                                                  const float* __restrict__ s,
                                                  float* __restrict__ out) {
  __shared__ __align__(16) float wS[12288];   // [16 co][64 ci][12] (slot9=bypass)
  __shared__ __align__(16) float sS[1920];    // s-band staging
  __shared__ __align__(16) float xS[1024];    // [2][4 pl][4*32] x-band
  int tid = threadIdx.x, blk = blockIdx.x;
  int b = blk >> 6, coT = (blk >> 3) & 7, band = blk & 7;
  {
    const float4* src = (const float4*)(WFlip + (size_t)coT * 12288);
    float4* d4 = (float4*)wS;
    for (int i = tid; i < 3072; i += 256) d4[i] = src[i];
  }
  for (int i = tid; i < 1920; i += 256) sS[i] = 0.f;
  int wv = tid >> 6, lane = tid & 63;
  int srow = lane >> 3, scol = lane & 7;
  int gr = band * 4 - 1 + srow;
  bool sv = (srow < 6) && (gr >= 0) && (gr < 32);
  const float* sbase = s + (size_t)(b * 64 + wv) * 1024 + gr * 32 + scol * 4;
  float* sd0 = sS + wv * 240 + srow * 40 + 4 + scol * 4;
  bool xv = (lane >= 48);
  int sub = lane - 48;
  int xr0 = sub >> 3, xc0 = sub & 7;
  int xr1 = (sub + 16) >> 3, xc1 = (sub + 16) & 7;
  const float* xbase = x + (size_t)(b * 64 + wv) * 1024 + band * 4 * 32;
  float* xd0 = xS + wv * 128;
  int co2 = tid >> 5;
  int pg = tid & 31;
  int row_l = pg >> 3, c0 = (pg & 7) * 4;
  const float* w0p = wS + (size_t)(co2 * 2) * 768;
  const float* w1p = w0p + 768;
  float a0[4] = {0, 0, 0, 0}, a1[4] = {0, 0, 0, 0};
  float4 stg, sx0, sx1;
  if (sv) stg = *(const float4*)(sbase);
  if (xv) {
    sx0 = *(const float4*)(xbase + xr0 * 32 + xc0 * 4);
    sx1 = *(const float4*)(xbase + xr1 * 32 + xc1 * 4);
  }
  __syncthreads();
  if (sv) *(float4*)sd0 = stg;
  if (xv) {
    *(float4*)(xd0 + xr0 * 32 + xc0 * 4) = sx0;
    *(float4*)(xd0 + xr1 * 32 + xc1 * 4) = sx1;
  }
  __syncthreads();
  for (int st = 0; st < 16; st += 2) {
    size_t po1 = (size_t)((st + 1) * 4) * 1024;
    if (sv) stg = *(const float4*)(sbase + po1);
    if (xv) {
      sx0 = *(const float4*)(xbase + po1 + xr0 * 32 + xc0 * 4);
      sx1 = *(const float4*)(xbase + po1 + xr1 * 32 + xc1 * 4);
    }
    conv3x2(sS, w0p, w1p, st * 4, row_l, c0, a0, a1);
#pragma unroll
    for (int cl = 0; cl < 4; ++cl) {
      float wb0 = w0p[(size_t)(st * 4 + cl) * 12 + 9];
      float wb1 = w1p[(size_t)(st * 4 + cl) * 12 + 9];
      float4 xq = *(const float4*)(xS + cl * 128 + row_l * 32 + c0);
      float xf[4] = {xq.x, xq.y, xq.z, xq.w};
#pragma unroll
      for (int k = 0; k < 4; ++k) {
        a0[k] = fmaf(xf[k], wb0, a0[k]);
        a1[k] = fmaf(xf[k], wb1, a1[k]);
      }
    }
    if (sv) *(float4*)(sd0 + 960) = stg;
    if (xv) {
      *(float4*)(xd0 + 512 + xr0 * 32 + xc0 * 4) = sx0;
      *(float4*)(xd0 + 512 + xr1 * 32 + xc1 * 4) = sx1;
    }
    __syncthreads();
    bool more = (st + 2 < 16);
    size_t po2 = (size_t)((st + 2) * 4) * 1024;
    if (more && sv) stg = *(const float4*)(sbase + po2);
    if (more && xv) {
      sx0 = *(const float4*)(xbase + po2 + xr0 * 32 + xc0 * 4);
      sx1 = *(const float4*)(xbase + po2 + xr1 * 32 + xc1 * 4);
    }
    conv3x2(sS + 960, w0p, w1p, (st + 1) * 4, row_l, c0, a0, a1);
#pragma unroll
    for (int cl = 0; cl < 4; ++cl) {
      float wb0 = w0p[(size_t)((st + 1) * 4 + cl) * 12 + 9];
      float wb1 = w1p[(size_t)((st + 1) * 4 + cl) * 12 + 9];
      float4 xq = *(const float4*)(xS + 512 + cl * 128 + row_l * 32 + c0);
      float xf[4] = {xq.x, xq.y, xq.z, xq.w};
#pragma unroll
      for (int k = 0; k < 4; ++k) {
        a0[k] = fmaf(xf[k], wb0, a0[k]);
        a1[k] = fmaf(xf[k], wb1, a1[k]);
      }
    }
    if (more && sv) *(float4*)sd0 = stg;
    if (more && xv) {
      *(float4*)(xd0 + xr0 * 32 + xc0 * 4) = sx0;
      *(float4*)(xd0 + xr1 * 32 + xc1 * 4) = sx1;
    }
    __syncthreads();
  }
  int gi = band * 4 + row_l;
  int co = coT * 16 + co2 * 2;
  size_t off0 = (size_t)(b * 128 + co) * 1024 + gi * 32 + c0;
  size_t off1 = off0 + 1024;
  float4 y0 = *(const float4*)(yp0 + off0);
  float4 y1 = *(const float4*)(yp0 + off1);
  float4 o0 = {a0[0] + y0.x, a0[1] + y0.y, a0[2] + y0.z, a0[3] + y0.w};
  float4 o1 = {a1[0] + y1.x, a1[1] + y1.y, a1[2] + y1.z, a1[3] + y1.w};
  *(float4*)(out + off0) = o0;
  *(float4*)(out + off1) = o1;
}

// ---- launch -----------------------------------------------------------------
extern "C" void kernel_launch(void* const* d_in, const int* in_sizes, int n_in,
                              void* d_out, int out_size, void* d_ws, size_t ws_size,
                              hipStream_t stream) {
  const float* x   = (const float*)d_in[0];
  const float* Wff = (const float*)d_in[1];
  const float* Wfb = (const float*)d_in[2];
  const float* Wb  = (const float*)d_in[3];
  float* out = (float*)d_out;

  float* yp0   = (float*)d_ws;                 // 524288
  float* V     = yp0 + 524288;                 // 3 * 262144
  float* G5    = V + (size_t)KRYLOV * VPLANE;  // 131072
  float* Gam   = G5 + 131072;                  // 16
  float* dvec  = Gam + 16;                     // 16
  float* WffP  = dvec + 16;                    // 98304
  float* WtF   = WffP + 98304;                 // 98304
  float* WFlip = WtF + 98304;                  // 98304

  hipLaunchKernelGGL(k_prep,    dim3(96),  dim3(256), 0, stream, Wff, Wfb, Wb, WffP, WtF, WFlip);
  hipLaunchKernelGGL(k_init,    dim3(256), dim3(256), 0, stream, x, WffP, yp0);
  hipLaunchKernelGGL(k_gram,    dim3(64),  dim3(256), 0, stream, Wfb, G5, Gam);
  hipLaunchKernelGGL(k_forward, dim3(256), dim3(256), 0, stream, x, WtF, yp0, V);
  for (int j = 0; j + 1 < KRYLOV; ++j) {
    hipLaunchKernelGGL(k_applyG, dim3(512), dim3(256), 0, stream,
                       V + (size_t)j * VPLANE, V + (size_t)(j + 1) * VPLANE, G5);
  }
  hipLaunchKernelGGL(k_gamma,   dim3(48),  dim3(256), 0, stream, V, Gam);
  hipLaunchKernelGGL(k_scalar,  dim3(1),   dim3(64),  0, stream, Gam, dvec);
  hipLaunchKernelGGL(k_combine, dim3(256), dim3(256), 0, stream, V, dvec);
  hipLaunchKernelGGL(k_finalize, dim3(256), dim3(256), 0, stream, x, WFlip, yp0, V, out);
}

// Round 7
// 305.311 us; speedup vs baseline: 5.2312x; 5.2054x over previous
//
#include <hip/hip_runtime.h>

#define NUM_ITERS 500
#define LR_F 0.001f
#define KRYLOV 3
#define VPLANE 262144    // 4*64*1024 floats per Krylov vector
// 500 = 20 segments * 25 steps; C(25,1)=25, C(25,2)=300, C(25,3)=2300

// ---- register-safe unpack helpers (scalar assigns keep arrays in VGPRs) -----
__device__ __forceinline__ void ldw12(const float* __restrict__ wp, float w[12]) {
  float4 q0 = ((const float4*)wp)[0];
  float4 q1 = ((const float4*)wp)[1];
  float4 q2 = ((const float4*)wp)[2];
  w[0] = q0.x; w[1] = q0.y; w[2] = q0.z; w[3] = q0.w;
  w[4] = q1.x; w[5] = q1.y; w[6] = q1.z; w[7] = q1.w;
  w[8] = q2.x; w[9] = q2.y; w[10] = q2.z; w[11] = q2.w;
}

__device__ __forceinline__ void ldrow8(const float* __restrict__ rp, float f[8]) {
  float2 p0 = *(const float2*)(rp);
  float2 p1 = *(const float2*)(rp + 2);
  float2 p2 = *(const float2*)(rp + 4);
  float2 p3 = *(const float2*)(rp + 6);
  f[0] = p0.x; f[1] = p0.y; f[2] = p1.x; f[3] = p1.y;
  f[4] = p2.x; f[5] = p2.y; f[6] = p3.x; f[7] = p3.y;
}

// round-3 measured-good helpers for k_applyG ----------------------------------
// load 25 (padded 28) weights for (och,o) from G row (stride 32, 16B aligned)
__device__ __forceinline__ void wload(const float* __restrict__ gb, int o, float w[28]) {
  const float4* g4 = (const float4*)(gb + o * 32);
#pragma unroll
  for (int i = 0; i < 7; ++i) {
    float4 v = g4[i];
    w[4 * i] = v.x; w[4 * i + 1] = v.y; w[4 * i + 2] = v.z; w[4 * i + 3] = v.w;
  }
}

// 5x5 conv tap loop: acc{0,1} for out cols cg*2 + {0,1}
__device__ __forceinline__ void conv5(const float* sbuf, int row_l, int cg, const float w[28],
                                      float& acc0, float& acc1) {
#pragma unroll
  for (int wr = 0; wr < 5; ++wr) {
    const float* rp = sbuf + (row_l + wr) * 40 + cg * 2 + 2;
    float2 p0 = *(const float2*)rp;
    float2 p1 = *(const float2*)(rp + 2);
    float2 p2 = *(const float2*)(rp + 4);
    float v[6] = {p0.x, p0.y, p1.x, p1.y, p2.x, p2.y};
#pragma unroll
    for (int vc = 0; vc < 5; ++vc) {
      acc0 = fmaf(w[wr * 5 + vc], v[vc], acc0);
      acc1 = fmaf(w[wr * 5 + vc], v[vc + 1], acc1);
    }
  }
}

// ---- weight prep: pad 9->12 (+transpose / +flip / +bypass slot) -------------
// grid 96 x 256 = 24576 tasks = 3 tables x 8192 (o,c) pairs
__global__ __launch_bounds__(256) void k_prep(const float* __restrict__ Wff,
                                              const float* __restrict__ Wfb,
                                              const float* __restrict__ Wb,
                                              float* __restrict__ WffP,
                                              float* __restrict__ WtF,
                                              float* __restrict__ WFlip) {
  int g = blockIdx.x * 256 + threadIdx.x;
  int table = g >> 13, t = g & 8191;
  float w[12];
#pragma unroll
  for (int k = 0; k < 12; ++k) w[k] = 0.f;
  float* dst;
  if (table == 0) {                       // WtF[o][c][12] = Wfb[(c*64+o)*9+k]
    int o = t >> 7, c = t & 127;
    const float* src = Wfb + (size_t)(c * 64 + o) * 9;
#pragma unroll
    for (int k = 0; k < 9; ++k) w[k] = src[k];
    dst = WtF + (size_t)t * 12;
  } else if (table == 1) {                // WffP[co*64+ci][12] = Wff[...*9+k]
    const float* src = Wff + (size_t)t * 9;
#pragma unroll
    for (int k = 0; k < 9; ++k) w[k] = src[k];
    dst = WffP + (size_t)t * 12;
  } else {                                // WFlip: flipped 3x3 + bypass in [9]
    const float* src = Wfb + (size_t)t * 9;
#pragma unroll
    for (int k = 0; k < 9; ++k) w[k] = src[8 - k];
    w[9] = Wb[t];
    dst = WFlip + (size_t)t * 12;
  }
  float4 v0 = {w[0], w[1], w[2], w[3]};
  float4 v1 = {w[4], w[5], w[6], w[7]};
  float4 v2 = {w[8], w[9], w[10], w[11]};
  ((float4*)dst)[0] = v0; ((float4*)dst)[1] = v1; ((float4*)dst)[2] = v2;
}

// ---- conv micro-bodies ------------------------------------------------------
// staged plane band: pitch 40, input col j at LDS col j+4 (halo zero).
// f[m] = input col c0-2+m ; 3x3 tap (di,dj) for px k needs m = k+dj+1.

__device__ __forceinline__ void conv3x2(const float* __restrict__ buf,   // 4 planes x 240
                                        const float* __restrict__ w0p,   // [ci][12]
                                        const float* __restrict__ w1p,
                                        int stci, int row_l, int c0,
                                        float a0[4], float a1[4]) {
#pragma unroll
  for (int cl = 0; cl < 4; ++cl) {
    float w0r[12], w1r[12];
    ldw12(w0p + (size_t)(stci + cl) * 12, w0r);
    ldw12(w1p + (size_t)(stci + cl) * 12, w1r);
    const float* pb = buf + cl * 240;
#pragma unroll
    for (int di = 0; di < 3; ++di) {
      float f[8];
      ldrow8(pb + (row_l + di) * 40 + c0 + 2, f);
#pragma unroll
      for (int dj = 0; dj < 3; ++dj) {
        float wa = w0r[di * 3 + dj], wb = w1r[di * 3 + dj];
#pragma unroll
        for (int k = 0; k < 4; ++k) {
          a0[k] = fmaf(f[k + dj + 1], wa, a0[k]);
          a1[k] = fmaf(f[k + dj + 1], wb, a1[k]);
        }
      }
    }
  }
}

__device__ __forceinline__ void conv3x1(const float* __restrict__ buf,
                                        const float* __restrict__ wp_base,  // [ci][12]
                                        int stci, int row_l, int c0, float a[4]) {
#pragma unroll
  for (int cl = 0; cl < 4; ++cl) {
    float wr[12];
    ldw12(wp_base + (size_t)(stci + cl) * 12, wr);
    const float* pb = buf + cl * 240;
#pragma unroll
    for (int di = 0; di < 3; ++di) {
      float f[8];
      ldrow8(pb + (row_l + di) * 40 + c0 + 2, f);
#pragma unroll
      for (int dj = 0; dj < 3; ++dj) {
        float wv = wr[di * 3 + dj];
#pragma unroll
        for (int k = 0; k < 4; ++k) a[k] = fmaf(f[k + dj + 1], wv, a[k]);
      }
    }
  }
}

// ---- k_init: yp0(unpadded 32x32) = relu(conv3x3 pad1(x, Wff)) ---------------
// grid 256 = b(2) | coT(3) | band(3); block: 16 co x 4 rows x 32 cols
__global__ __launch_bounds__(256) void k_init(const float* __restrict__ x,
                                              const float* __restrict__ WffP,
                                              float* __restrict__ yp0) {
  __shared__ __align__(16) float wS[12288];   // [16 co][64 ci][12]
  __shared__ __align__(16) float sS[1920];    // [2][4 pl][6*40]
  int tid = threadIdx.x, blk = blockIdx.x;
  int b = blk >> 6, coT = (blk >> 3) & 7, band = blk & 7;
  {
    const float4* src = (const float4*)(WffP + (size_t)coT * 12288);
    float4* d4 = (float4*)wS;
    for (int i = tid; i < 3072; i += 256) d4[i] = src[i];
  }
  for (int i = tid; i < 1920; i += 256) sS[i] = 0.f;
  int wv = tid >> 6, lane = tid & 63;
  int srow = lane >> 3, scol = lane & 7;
  int gr = band * 4 - 1 + srow;
  bool sv = (srow < 6) && (gr >= 0) && (gr < 32);
  const float* sbase = x + (size_t)(b * 64 + wv) * 1024 + gr * 32 + scol * 4;
  float* sd0 = sS + wv * 240 + srow * 40 + 4 + scol * 4;
  int co2 = tid >> 5;                 // 0..7 -> co pair
  int pg = tid & 31;
  int row_l = pg >> 3, c0 = (pg & 7) * 4;
  const float* w0p = wS + (size_t)(co2 * 2) * 768;
  const float* w1p = w0p + 768;
  float a0[4] = {0, 0, 0, 0}, a1[4] = {0, 0, 0, 0};
  float4 stg;
  if (sv) stg = *(const float4*)(sbase);
  __syncthreads();
  if (sv) *(float4*)sd0 = stg;
  __syncthreads();
  for (int st = 0; st < 16; st += 2) {
    if (sv) stg = *(const float4*)(sbase + (size_t)((st + 1) * 4) * 1024);
    conv3x2(sS, w0p, w1p, st * 4, row_l, c0, a0, a1);
    if (sv) *(float4*)(sd0 + 960) = stg;
    __syncthreads();
    bool more = (st + 2 < 16);
    if (more && sv) stg = *(const float4*)(sbase + (size_t)((st + 2) * 4) * 1024);
    conv3x2(sS + 960, w0p, w1p, (st + 1) * 4, row_l, c0, a0, a1);
    if (more && sv) *(float4*)sd0 = stg;
    __syncthreads();
  }
  int gi = band * 4 + row_l;
  int co = coT * 16 + co2 * 2;
  float4 o0 = {a0[0] > 0.f ? a0[0] : 0.f, a0[1] > 0.f ? a0[1] : 0.f,
               a0[2] > 0.f ? a0[2] : 0.f, a0[3] > 0.f ? a0[3] : 0.f};
  float4 o1 = {a1[0] > 0.f ? a1[0] : 0.f, a1[1] > 0.f ? a1[1] : 0.f,
               a1[2] > 0.f ? a1[2] : 0.f, a1[3] > 0.f ? a1[3] : 0.f};
  *(float4*)(yp0 + (size_t)(b * 128 + co) * 1024 + gi * 32 + c0) = o0;
  *(float4*)(yp0 + (size_t)(b * 128 + co + 1) * 1024 + gi * 32 + c0) = o1;
}

// ---- k_gram: G[(o'*64+o)*32 + tap] (5x5 Gram of Wfb), zero pad+Gam ---------
__global__ __launch_bounds__(256) void k_gram(const float* __restrict__ Wfb,
                                              float* __restrict__ G,
                                              float* __restrict__ Gam) {
  __shared__ float wA[128 * 9];
  __shared__ float gred[256][25];
  int tid = threadIdx.x;
  int op = blockIdx.x;
  if (blockIdx.x == 0 && tid < 16) Gam[tid] = 0.f;
  for (int i = tid; i < 1152; i += 256) {
    int c = i / 9, k = i - c * 9;
    wA[i] = Wfb[(size_t)(c * 64 + op) * 9 + k];
  }
  __syncthreads();
  int o = tid & 63, part = tid >> 6;
  float g[25];
#pragma unroll
  for (int i = 0; i < 25; ++i) g[i] = 0.f;
  for (int c = part * 32; c < part * 32 + 32; ++c) {
    float b9[9];
#pragma unroll
    for (int k = 0; k < 9; ++k) b9[k] = Wfb[(size_t)(c * 64 + o) * 9 + k];
    const float* a9 = &wA[c * 9];
#pragma unroll
    for (int ei = 0; ei < 3; ++ei)
#pragma unroll
      for (int ej = 0; ej < 3; ++ej) {
        float av = a9[ei * 3 + ej];
#pragma unroll
        for (int di = 0; di < 3; ++di)
#pragma unroll
          for (int dj = 0; dj < 3; ++dj)
            g[(ei - di + 2) * 5 + (ej - dj + 2)] = fmaf(av, b9[di * 3 + dj],
                                                        g[(ei - di + 2) * 5 + (ej - dj + 2)]);
      }
  }
#pragma unroll
  for (int i = 0; i < 25; ++i) gred[tid][i] = g[i];
  __syncthreads();
  if (part == 0) {
    float* dst = G + ((size_t)op * 64 + o) * 32;
#pragma unroll
    for (int i = 0; i < 25; ++i)
      dst[i] = gred[tid][i] + gred[tid + 64][i] + gred[tid + 128][i] + gred[tid + 192][i];
#pragma unroll
    for (int i = 25; i < 32; ++i) dst[i] = 0.f;
  }
}

// ---- k_forward: v0 = x - conv3x3 pad1(yp0, WtF) -----------------------------
// grid 256 = b(2) | oT(3) | band(3); block: 8 och x 4 rows x 32 cols; 32 steps
__global__ __launch_bounds__(256) void k_forward(const float* __restrict__ x,
                                                 const float* __restrict__ WtF,
                                                 const float* __restrict__ yp0,
                                                 float* __restrict__ v0) {
  __shared__ __align__(16) float wS[12288];   // [8 och][128 ci][12]
  __shared__ __align__(16) float sS[1920];
  int tid = threadIdx.x, blk = blockIdx.x;
  int b = blk >> 6, oT = (blk >> 3) & 7, band = blk & 7;
  {
    const float4* src = (const float4*)(WtF + (size_t)oT * 12288);
    float4* d4 = (float4*)wS;
    for (int i = tid; i < 3072; i += 256) d4[i] = src[i];
  }
  for (int i = tid; i < 1920; i += 256) sS[i] = 0.f;
  int wv = tid >> 6, lane = tid & 63;
  int srow = lane >> 3, scol = lane & 7;
  int gr = band * 4 - 1 + srow;
  bool sv = (srow < 6) && (gr >= 0) && (gr < 32);
  const float* sbase = yp0 + (size_t)(b * 128 + wv) * 1024 + gr * 32 + scol * 4;
  float* sd0 = sS + wv * 240 + srow * 40 + 4 + scol * 4;
  int och_l = tid >> 5;               // 0..7
  int pg = tid & 31;
  int row_l = pg >> 3, c0 = (pg & 7) * 4;
  const float* wp_base = wS + (size_t)och_l * 1536;   // 128*12
  float acc[4] = {0, 0, 0, 0};
  float4 stg;
  if (sv) stg = *(const float4*)(sbase);
  __syncthreads();
  if (sv) *(float4*)sd0 = stg;
  __syncthreads();
  for (int st = 0; st < 32; st += 2) {
    if (sv) stg = *(const float4*)(sbase + (size_t)((st + 1) * 4) * 1024);
    conv3x1(sS, wp_base, st * 4, row_l, c0, acc);
    if (sv) *(float4*)(sd0 + 960) = stg;
    __syncthreads();
    bool more = (st + 2 < 32);
    if (more && sv) stg = *(const float4*)(sbase + (size_t)((st + 2) * 4) * 1024);
    conv3x1(sS + 960, wp_base, (st + 1) * 4, row_l, c0, acc);
    if (more && sv) *(float4*)sd0 = stg;
    __syncthreads();
  }
  int gi = band * 4 + row_l;
  int och = oT * 8 + och_l;
  size_t off = (size_t)(b * 64 + och) * 1024 + gi * 32 + c0;
  float4 xv = *(const float4*)(x + off);
  float4 rv = {xv.x - acc[0], xv.y - acc[1], xv.z - acc[2], xv.w - acc[3]};
  *(float4*)(v0 + off) = rv;
}

// ---- k_applyG: v_{j+1} = G (*) v_j (5x5 pad2, 64->64ch) ---------------------
// ROUND-3 measured-good version: global wload double-buffer, no LDS weight
// cache, plain launch_bounds(256) (the (256,2)+LDS-weights variant spilled
// ~10KB/thread to scratch -> 724us; this one ran in a ~46us envelope).
// grid 512 = b(2) | och_t(4b) | row_t(3b). Block: 4 och x 4 rows x 32 cols.
__global__ __launch_bounds__(256) void k_applyG(const float* __restrict__ vin,
                                                float* __restrict__ vout,
                                                const float* __restrict__ G) {
  __shared__ __align__(16) float sIn[2][8 * 40];
  int tid = threadIdx.x;
  int blk = blockIdx.x;
  int b = blk >> 7, och_t = (blk >> 3) & 15, row_t = blk & 7;
  int wv = __builtin_amdgcn_readfirstlane(tid >> 6);
  int och = och_t * 4 + wv;
  int row_l = (tid >> 4) & 3;
  int cg = tid & 15;
  for (int i = tid; i < 2 * 320; i += 256) ((float*)sIn)[i] = 0.f;
  bool stager = ((tid & 3) == 0);
  int task = tid >> 2;
  int srow = task >> 3, scg = task & 7;
  int gr = row_t * 4 - 2 + srow;
  bool srv = stager && gr >= 0 && gr < 32;
  const float* rbase = vin + ((long)(b * 64) * 1024 + (long)gr * 32 + scg * 4);
  float* sdst = &sIn[0][srow * 40 + 4 + scg * 4];
  const float* gb = G + (size_t)och * 64 * 32;
  float wA[28], wB[28];
  float acc0 = 0.f, acc1 = 0.f;
  float4 stg;
  if (srv) stg = *(const float4*)(rbase);
  wload(gb, 0, wA);
  __syncthreads();
  if (srv) *(float4*)(sdst) = stg;
  __syncthreads();
  for (int o = 0; o < 64; o += 2) {
    if (srv) stg = *(const float4*)(rbase + (size_t)(o + 1) * 1024);
    wload(gb, o + 1, wB);
    conv5(sIn[0], row_l, cg, wA, acc0, acc1);
    if (srv) *(float4*)(sdst + 320) = stg;
    __syncthreads();
    bool more = (o + 2 < 64);
    if (more) {
      if (srv) stg = *(const float4*)(rbase + (size_t)(o + 2) * 1024);
      wload(gb, o + 2, wA);
    }
    conv5(sIn[1], row_l, cg, wB, acc0, acc1);
    if (more && srv) *(float4*)(sdst) = stg;
    __syncthreads();
  }
  int gi = row_t * 4 + row_l;
  size_t own = ((size_t)(b * 64 + och) * 32 + gi) * 32 + cg * 2;
  float2 ov = {acc0, acc1};
  *(float2*)(vout + own) = ov;
}

// ---- k_gamma: Gam[i][j] = <v_i, v_j>; grid 6 pairs x 8 slices ---------------
__global__ __launch_bounds__(256) void k_gamma(const float* __restrict__ V,
                                               float* __restrict__ Gam) {
  __shared__ float ws4[4];
  int tid = threadIdx.x;
  int p = blockIdx.x >> 3, slice = blockIdx.x & 7;
  int i = 0, rem = p;
  while (rem >= KRYLOV - i) { rem -= KRYLOV - i; ++i; }
  int j = i + rem;
  const float4* vi = (const float4*)(V + (size_t)i * VPLANE);
  const float4* vj = (const float4*)(V + (size_t)j * VPLANE);
  int base = slice * 8192;
  float acc = 0.f;
  for (int t = tid; t < 8192; t += 256) {
    float4 a = vi[base + t], c = vj[base + t];
    acc = fmaf(a.x, c.x, acc);
    acc = fmaf(a.y, c.y, acc);
    acc = fmaf(a.z, c.z, acc);
    acc = fmaf(a.w, c.w, acc);
  }
#pragma unroll
  for (int d = 32; d; d >>= 1) acc += __shfl_down(acc, d, 64);
  if ((tid & 63) == 0) ws4[tid >> 6] = acc;
  __syncthreads();
  if (tid == 0) {
    float tot = ws4[0] + ws4[1] + ws4[2] + ws4[3];
    atomicAdd(&Gam[i * KRYLOV + j], tot);
    if (i != j) atomicAdd(&Gam[j * KRYLOV + i], tot);
  }
}

// ---- k_scalar: 20 closed-form segments of 25 constant-alpha steps -----------
// c <- (I-aS)^25 c = c -25a Sc +300a^2 S^2c ; d += a[25c -300a Sc +2300a^2 S^2c]
__global__ __launch_bounds__(64) void k_scalar(const float* __restrict__ Gam,
                                               float* __restrict__ dvec) {
  float g00 = Gam[0], g01 = Gam[1], g02 = Gam[2];
  float g11 = Gam[4], g12 = Gam[5], g22 = Gam[8];
  float c0 = 1.f, c1 = 0.f, c2 = 0.f;
  float d0 = 0.f, d1 = 0.f, d2 = 0.f;
#pragma unroll
  for (int seg = 0; seg < 20; ++seg) {
    float pr = g00 * c0 * c0 + g11 * c1 * c1 + g22 * c2 * c2 +
               2.f * (g01 * c0 * c1 + g02 * c0 * c2 + g12 * c1 * c2);
    float a = LR_F * __builtin_amdgcn_rsqf(pr);
    float a2 = a * a, a3 = a2 * a;
    d0 += 25.f * a * c0;
    d1 += 25.f * a * c1 - 300.f * a2 * c0;
    d2 += 25.f * a * c2 - 300.f * a2 * c1 + 2300.f * a3 * c0;
    float t1 = c1 - 25.f * a * c0;
    float t2 = c2 - 25.f * a * c1 + 300.f * a2 * c0;
    c1 = t1; c2 = t2;
  }
  if (threadIdx.x == 0) { dvec[0] = d0; dvec[1] = d1; dvec[2] = d2; }
}

// ---- k_combine: s = sum_j d_j v_j (in place over v_0) -----------------------
__global__ __launch_bounds__(256) void k_combine(float* __restrict__ V,
                                                 const float* __restrict__ dvec) {
  int idx = blockIdx.x * 256 + threadIdx.x;
  float d[KRYLOV];
#pragma unroll
  for (int i = 0; i < KRYLOV; ++i) d[i] = dvec[i];
  float4 acc = {0.f, 0.f, 0.f, 0.f};
#pragma unroll
  for (int i = 0; i < KRYLOV; ++i) {
    float4 v = *(const float4*)(V + (size_t)i * VPLANE + (size_t)idx * 4);
    acc.x = fmaf(d[i], v.x, acc.x);
    acc.y = fmaf(d[i], v.y, acc.y);
    acc.z = fmaf(d[i], v.z, acc.z);
    acc.w = fmaf(d[i], v.w, acc.w);
  }
  *(float4*)(V + (size_t)idx * 4) = acc;
}

// ---- k_finalize: out = yp0 + conv3x3 pad1(s, WFlip) + 1x1(x, Wb slot9) ------
// grid 256 = b(2) | coT(3) | band(3); block: 16 co x 4 rows x 32 cols; 16 steps
__global__ __launch_bounds__(256) void k_finalize(const float* __restrict__ x,
                                                  const float* __restrict__ WFlip,
                                                  const float* __restrict__ yp0,
                                                  const float* __restrict__ s,
                                                  float* __restrict__ out) {
  __shared__ __align__(16) float wS[12288];   // [16 co][64 ci][12] (slot9=bypass)
  __shared__ __align__(16) float sS[1920];    // s-band staging
  __shared__ __align__(16) float xS[1024];    // [2][4 pl][4*32] x-band
  int tid = threadIdx.x, blk = blockIdx.x;
  int b = blk >> 6, coT = (blk >> 3) & 7, band = blk & 7;
  {
    const float4* src = (const float4*)(WFlip + (size_t)coT * 12288);
    float4* d4 = (float4*)wS;
    for (int i = tid; i < 3072; i += 256) d4[i] = src[i];
  }
  for (int i = tid; i < 1920; i += 256) sS[i] = 0.f;
  int wv = tid >> 6, lane = tid & 63;
  int srow = lane >> 3, scol = lane & 7;
  int gr = band * 4 - 1 + srow;
  bool sv = (srow < 6) && (gr >= 0) && (gr < 32);
  const float* sbase = s + (size_t)(b * 64 + wv) * 1024 + gr * 32 + scol * 4;
  float* sd0 = sS + wv * 240 + srow * 40 + 4 + scol * 4;
  bool xv = (lane >= 48);
  int sub = lane - 48;
  int xr0 = sub >> 3, xc0 = sub & 7;
  int xr1 = (sub + 16) >> 3, xc1 = (sub + 16) & 7;
  const float* xbase = x + (size_t)(b * 64 + wv) * 1024 + band * 4 * 32;
  float* xd0 = xS + wv * 128;
  int co2 = tid >> 5;
  int pg = tid & 31;
  int row_l = pg >> 3, c0 = (pg & 7) * 4;
  const float* w0p = wS + (size_t)(co2 * 2) * 768;
  const float* w1p = w0p + 768;
  float a0[4] = {0, 0, 0, 0}, a1[4] = {0, 0, 0, 0};
  float4 stg, sx0, sx1;
  if (sv) stg = *(const float4*)(sbase);
  if (xv) {
    sx0 = *(const float4*)(xbase + xr0 * 32 + xc0 * 4);
    sx1 = *(const float4*)(xbase + xr1 * 32 + xc1 * 4);
  }
  __syncthreads();
  if (sv) *(float4*)sd0 = stg;
  if (xv) {
    *(float4*)(xd0 + xr0 * 32 + xc0 * 4) = sx0;
    *(float4*)(xd0 + xr1 * 32 + xc1 * 4) = sx1;
  }
  __syncthreads();
  for (int st = 0; st < 16; st += 2) {
    size_t po1 = (size_t)((st + 1) * 4) * 1024;
    if (sv) stg = *(const float4*)(sbase + po1);
    if (xv) {
      sx0 = *(const float4*)(xbase + po1 + xr0 * 32 + xc0 * 4);
      sx1 = *(const float4*)(xbase + po1 + xr1 * 32 + xc1 * 4);
    }
    conv3x2(sS, w0p, w1p, st * 4, row_l, c0, a0, a1);
#pragma unroll
    for (int cl = 0; cl < 4; ++cl) {
      float wb0 = w0p[(size_t)(st * 4 + cl) * 12 + 9];
      float wb1 = w1p[(size_t)(st * 4 + cl) * 12 + 9];
      float4 xq = *(const float4*)(xS + cl * 128 + row_l * 32 + c0);
      float xf[4] = {xq.x, xq.y, xq.z, xq.w};
#pragma unroll
      for (int k = 0; k < 4; ++k) {
        a0[k] = fmaf(xf[k], wb0, a0[k]);
        a1[k] = fmaf(xf[k], wb1, a1[k]);
      }
    }
    if (sv) *(float4*)(sd0 + 960) = stg;
    if (xv) {
      *(float4*)(xd0 + 512 + xr0 * 32 + xc0 * 4) = sx0;
      *(float4*)(xd0 + 512 + xr1 * 32 + xc1 * 4) = sx1;
    }
    __syncthreads();
    bool more = (st + 2 < 16);
    size_t po2 = (size_t)((st + 2) * 4) * 1024;
    if (more && sv) stg = *(const float4*)(sbase + po2);
    if (more && xv) {
      sx0 = *(const float4*)(xbase + po2 + xr0 * 32 + xc0 * 4);
      sx1 = *(const float4*)(xbase + po2 + xr1 * 32 + xc1 * 4);
    }
    conv3x2(sS + 960, w0p, w1p, (st + 1) * 4, row_l, c0, a0, a1);
#pragma unroll
    for (int cl = 0; cl < 4; ++cl) {
      float wb0 = w0p[(size_t)((st + 1) * 4 + cl) * 12 + 9];
      float wb1 = w1p[(size_t)((st + 1) * 4 + cl) * 12 + 9];
      float4 xq = *(const float4*)(xS + 512 + cl * 128 + row_l * 32 + c0);
      float xf[4] = {xq.x, xq.y, xq.z, xq.w};
#pragma unroll
      for (int k = 0; k < 4; ++k) {
        a0[k] = fmaf(xf[k], wb0, a0[k]);
        a1[k] = fmaf(xf[k], wb1, a1[k]);
      }
    }
    if (more && sv) *(float4*)sd0 = stg;
    if (more && xv) {
      *(float4*)(xd0 + xr0 * 32 + xc0 * 4) = sx0;
      *(float4*)(xd0 + xr1 * 32 + xc1 * 4) = sx1;
    }
    __syncthreads();
  }
  int gi = band * 4 + row_l;
  int co = coT * 16 + co2 * 2;
  size_t off0 = (size_t)(b * 128 + co) * 1024 + gi * 32 + c0;
  size_t off1 = off0 + 1024;
  float4 y0 = *(const float4*)(yp0 + off0);
  float4 y1 = *(const float4*)(yp0 + off1);
  float4 o0 = {a0[0] + y0.x, a0[1] + y0.y, a0[2] + y0.z, a0[3] + y0.w};
  float4 o1 = {a1[0] + y1.x, a1[1] + y1.y, a1[2] + y1.z, a1[3] + y1.w};
  *(float4*)(out + off0) = o0;
  *(float4*)(out + off1) = o1;
}

// ---- launch -----------------------------------------------------------------
extern "C" void kernel_launch(void* const* d_in, const int* in_sizes, int n_in,
                              void* d_out, int out_size, void* d_ws, size_t ws_size,
                              hipStream_t stream) {
  const float* x   = (const float*)d_in[0];
  const float* Wff = (const float*)d_in[1];
  const float* Wfb = (const float*)d_in[2];
  const float* Wb  = (const float*)d_in[3];
  float* out = (float*)d_out;

  float* yp0   = (float*)d_ws;                 // 524288
  float* V     = yp0 + 524288;                 // 3 * 262144
  float* G5    = V + (size_t)KRYLOV * VPLANE;  // 131072
  float* Gam   = G5 + 131072;                  // 16
  float* dvec  = Gam + 16;                     // 16
  float* WffP  = dvec + 16;                    // 98304
  float* WtF   = WffP + 98304;                 // 98304
  float* WFlip = WtF + 98304;                  // 98304

  hipLaunchKernelGGL(k_prep,    dim3(96),  dim3(256), 0, stream, Wff, Wfb, Wb, WffP, WtF, WFlip);
  hipLaunchKernelGGL(k_init,    dim3(256), dim3(256), 0, stream, x, WffP, yp0);
  hipLaunchKernelGGL(k_gram,    dim3(64),  dim3(256), 0, stream, Wfb, G5, Gam);
  hipLaunchKernelGGL(k_forward, dim3(256), dim3(256), 0, stream, x, WtF, yp0, V);
  for (int j = 0; j + 1 < KRYLOV; ++j) {
    hipLaunchKernelGGL(k_applyG, dim3(512), dim3(256), 0, stream,
                       V + (size_t)j * VPLANE, V + (size_t)(j + 1) * VPLANE, G5);
  }
  hipLaunchKernelGGL(k_gamma,   dim3(48),  dim3(256), 0, stream, V, Gam);
  hipLaunchKernelGGL(k_scalar,  dim3(1),   dim3(64),  0, stream, Gam, dvec);
  hipLaunchKernelGGL(k_combine, dim3(256), dim3(256), 0, stream, V, dvec);
  hipLaunchKernelGGL(k_finalize, dim3(256), dim3(256), 0, stream, x, WFlip, yp0, V, out);
}

// Round 8
// 293.299 us; speedup vs baseline: 5.4454x; 1.0410x over previous
//
#include <hip/hip_runtime.h>

#define NUM_ITERS 500
#define LR_F 0.001f
#define KRYLOV 3
#define VPLANE 262144    // 4*64*1024 floats per Krylov vector
// 500 = 20 segments * 25 steps; C(25,1)=25, C(25,2)=300, C(25,3)=2300

// ---- register-safe unpack helpers -------------------------------------------
__device__ __forceinline__ void ldw12(const float* __restrict__ wp, float w[12]) {
  float4 q0 = ((const float4*)wp)[0];
  float4 q1 = ((const float4*)wp)[1];
  float4 q2 = ((const float4*)wp)[2];
  w[0] = q0.x; w[1] = q0.y; w[2] = q0.z; w[3] = q0.w;
  w[4] = q1.x; w[5] = q1.y; w[6] = q1.z; w[7] = q1.w;
  w[8] = q2.x; w[9] = q2.y; w[10] = q2.z; w[11] = q2.w;
}

// aligned b128 pair: f[0..7] = LDS words rp..rp+7 (rp 4-word aligned) --------
__device__ __forceinline__ void ldrow8b(const float* __restrict__ rp, float f[8]) {
  float4 a = *(const float4*)(rp);
  float4 b = *(const float4*)(rp + 4);
  f[0] = a.x; f[1] = a.y; f[2] = a.z; f[3] = a.w;
  f[4] = b.x; f[5] = b.y; f[6] = b.z; f[7] = b.w;
}

// round-3 measured-good helpers for k_applyG ----------------------------------
__device__ __forceinline__ void wload(const float* __restrict__ gb, int o, float w[28]) {
  const float4* g4 = (const float4*)(gb + o * 32);
#pragma unroll
  for (int i = 0; i < 7; ++i) {
    float4 v = g4[i];
    w[4 * i] = v.x; w[4 * i + 1] = v.y; w[4 * i + 2] = v.z; w[4 * i + 3] = v.w;
  }
}

__device__ __forceinline__ void conv5(const float* sbuf, int row_l, int cg, const float w[28],
                                      float& acc0, float& acc1) {
#pragma unroll
  for (int wr = 0; wr < 5; ++wr) {
    const float* rp = sbuf + (row_l + wr) * 40 + cg * 2 + 2;
    float2 p0 = *(const float2*)rp;
    float2 p1 = *(const float2*)(rp + 2);
    float2 p2 = *(const float2*)(rp + 4);
    float v[6] = {p0.x, p0.y, p1.x, p1.y, p2.x, p2.y};
#pragma unroll
    for (int vc = 0; vc < 5; ++vc) {
      acc0 = fmaf(w[wr * 5 + vc], v[vc], acc0);
      acc1 = fmaf(w[wr * 5 + vc], v[vc + 1], acc1);
    }
  }
}

// ---- weight prep ------------------------------------------------------------
// table0: WtF2[ciQ(4)][oT(4)][o16(16)][ci32(32)][12]  (forward, transposed)
// table1: WffP[co*64+ci][12]      table2: WFlip (flipped 3x3 + bypass slot 9)
__global__ __launch_bounds__(256) void k_prep(const float* __restrict__ Wff,
                                              const float* __restrict__ Wfb,
                                              const float* __restrict__ Wb,
                                              float* __restrict__ WffP,
                                              float* __restrict__ WtF,
                                              float* __restrict__ WFlip) {
  int g = blockIdx.x * 256 + threadIdx.x;
  int table = g >> 13, t = g & 8191;
  float w[12];
#pragma unroll
  for (int k = 0; k < 12; ++k) w[k] = 0.f;
  float* dst;
  if (table == 0) {
    int o = t >> 7, c = t & 127;
    const float* src = Wfb + (size_t)(c * 64 + o) * 9;
#pragma unroll
    for (int k = 0; k < 9; ++k) w[k] = src[k];
    int ciQ = c >> 5, ci32 = c & 31, oT = o >> 4, o16 = o & 15;
    dst = WtF + ((size_t)(((ciQ * 4 + oT) * 16 + o16) * 32) + ci32) * 12;
  } else if (table == 1) {
    const float* src = Wff + (size_t)t * 9;
#pragma unroll
    for (int k = 0; k < 9; ++k) w[k] = src[k];
    dst = WffP + (size_t)t * 12;
  } else {
    const float* src = Wfb + (size_t)t * 9;
#pragma unroll
    for (int k = 0; k < 9; ++k) w[k] = src[8 - k];
    w[9] = Wb[t];
    dst = WFlip + (size_t)t * 12;
  }
  float4 v0 = {w[0], w[1], w[2], w[3]};
  float4 v1 = {w[4], w[5], w[6], w[7]};
  float4 v2 = {w[8], w[9], w[10], w[11]};
  ((float4*)dst)[0] = v0; ((float4*)dst)[1] = v1; ((float4*)dst)[2] = v2;
}

// ---- conv3x2: input col j at LDS col j+2 (halo+2), pitch 40 -----------------
// f[m] = input col c0-2+m; tap (di,dj) for px k uses f[k+dj+1]. Reads are two
// aligned b128 per row -> conflict-free (prev b64@+2 pattern was 4-way).
__device__ __forceinline__ void conv3x2(const float* __restrict__ buf,   // 4 planes x 240
                                        const float* __restrict__ w0p,   // [ci][12]
                                        const float* __restrict__ w1p,
                                        int stci, int row_l, int c0,
                                        float a0[4], float a1[4]) {
#pragma unroll
  for (int cl = 0; cl < 4; ++cl) {
    float w0r[12], w1r[12];
    ldw12(w0p + (size_t)(stci + cl) * 12, w0r);
    ldw12(w1p + (size_t)(stci + cl) * 12, w1r);
    const float* pb = buf + cl * 240;
#pragma unroll
    for (int di = 0; di < 3; ++di) {
      float f[8];
      ldrow8b(pb + (row_l + di) * 40 + c0, f);
#pragma unroll
      for (int dj = 0; dj < 3; ++dj) {
        float wa = w0r[di * 3 + dj], wb = w1r[di * 3 + dj];
#pragma unroll
        for (int k = 0; k < 4; ++k) {
          a0[k] = fmaf(f[k + dj + 1], wa, a0[k]);
          a1[k] = fmaf(f[k + dj + 1], wb, a1[k]);
        }
      }
    }
  }
}

// staging write helper: float4 -> LDS word addr == 2 (mod 4), as two float2
__device__ __forceinline__ void stg_write(float* sd, float4 v) {
  float2 u = {v.x, v.y}, w = {v.z, v.w};
  *(float2*)sd = u;
  *(float2*)(sd + 2) = w;
}

// ---- k_init: yp0(32x32) = relu(conv3x3 pad1(x, Wff)) ------------------------
// grid 256 = b(2) | coT(3) | band(3); block: 16 co x 4 rows x 32 cols
__global__ __launch_bounds__(256) void k_init(const float* __restrict__ x,
                                              const float* __restrict__ WffP,
                                              float* __restrict__ yp0) {
  __shared__ __align__(16) float wS[12288];   // [16 co][64 ci][12]
  __shared__ __align__(16) float sS[1920];    // [2][4 pl][6*40]
  int tid = threadIdx.x, blk = blockIdx.x;
  int b = blk >> 6, coT = (blk >> 3) & 7, band = blk & 7;
  {
    const float4* src = (const float4*)(WffP + (size_t)coT * 12288);
    float4* d4 = (float4*)wS;
    for (int i = tid; i < 3072; i += 256) d4[i] = src[i];
  }
  for (int i = tid; i < 1920; i += 256) sS[i] = 0.f;
  int wv = tid >> 6, lane = tid & 63;
  int srow = lane >> 3, scol = lane & 7;
  int gr = band * 4 - 1 + srow;
  bool sv = (srow < 6) && (gr >= 0) && (gr < 32);
  const float* sbase = x + (size_t)(b * 64 + wv) * 1024 + gr * 32 + scol * 4;
  float* sd0 = sS + wv * 240 + srow * 40 + 2 + scol * 4;
  int co2 = tid >> 5;
  int pg = tid & 31;
  int row_l = pg >> 3, c0 = (pg & 7) * 4;
  const float* w0p = wS + (size_t)(co2 * 2) * 768;
  const float* w1p = w0p + 768;
  float a0[4] = {0, 0, 0, 0}, a1[4] = {0, 0, 0, 0};
  float4 stg;
  if (sv) stg = *(const float4*)(sbase);
  __syncthreads();
  if (sv) stg_write(sd0, stg);
  __syncthreads();
  for (int st = 0; st < 16; st += 2) {
    if (sv) stg = *(const float4*)(sbase + (size_t)((st + 1) * 4) * 1024);
    conv3x2(sS, w0p, w1p, st * 4, row_l, c0, a0, a1);
    if (sv) stg_write(sd0 + 960, stg);
    __syncthreads();
    bool more = (st + 2 < 16);
    if (more && sv) stg = *(const float4*)(sbase + (size_t)((st + 2) * 4) * 1024);
    conv3x2(sS + 960, w0p, w1p, (st + 1) * 4, row_l, c0, a0, a1);
    if (more && sv) stg_write(sd0, stg);
    __syncthreads();
  }
  int gi = band * 4 + row_l;
  int co = coT * 16 + co2 * 2;
  float4 o0 = {a0[0] > 0.f ? a0[0] : 0.f, a0[1] > 0.f ? a0[1] : 0.f,
               a0[2] > 0.f ? a0[2] : 0.f, a0[3] > 0.f ? a0[3] : 0.f};
  float4 o1 = {a1[0] > 0.f ? a1[0] : 0.f, a1[1] > 0.f ? a1[1] : 0.f,
               a1[2] > 0.f ? a1[2] : 0.f, a1[3] > 0.f ? a1[3] : 0.f};
  *(float4*)(yp0 + (size_t)(b * 128 + co) * 1024 + gi * 32 + c0) = o0;
  *(float4*)(yp0 + (size_t)(b * 128 + co + 1) * 1024 + gi * 32 + c0) = o1;
}

// ---- k_gram: 5x5 Gram of Wfb ------------------------------------------------
__global__ __launch_bounds__(256) void k_gram(const float* __restrict__ Wfb,
                                              float* __restrict__ G,
                                              float* __restrict__ Gam) {
  __shared__ float wA[128 * 9];
  __shared__ float gred[256][25];
  int tid = threadIdx.x;
  int op = blockIdx.x;
  if (blockIdx.x == 0 && tid < 16) Gam[tid] = 0.f;
  for (int i = tid; i < 1152; i += 256) {
    int c = i / 9, k = i - c * 9;
    wA[i] = Wfb[(size_t)(c * 64 + op) * 9 + k];
  }
  __syncthreads();
  int o = tid & 63, part = tid >> 6;
  float g[25];
#pragma unroll
  for (int i = 0; i < 25; ++i) g[i] = 0.f;
  for (int c = part * 32; c < part * 32 + 32; ++c) {
    float b9[9];
#pragma unroll
    for (int k = 0; k < 9; ++k) b9[k] = Wfb[(size_t)(c * 64 + o) * 9 + k];
    const float* a9 = &wA[c * 9];
#pragma unroll
    for (int ei = 0; ei < 3; ++ei)
#pragma unroll
      for (int ej = 0; ej < 3; ++ej) {
        float av = a9[ei * 3 + ej];
#pragma unroll
        for (int di = 0; di < 3; ++di)
#pragma unroll
          for (int dj = 0; dj < 3; ++dj)
            g[(ei - di + 2) * 5 + (ej - dj + 2)] = fmaf(av, b9[di * 3 + dj],
                                                        g[(ei - di + 2) * 5 + (ej - dj + 2)]);
      }
  }
#pragma unroll
  for (int i = 0; i < 25; ++i) gred[tid][i] = g[i];
  __syncthreads();
  if (part == 0) {
    float* dst = G + ((size_t)op * 64 + o) * 32;
#pragma unroll
    for (int i = 0; i < 25; ++i)
      dst[i] = gred[tid][i] + gred[tid + 64][i] + gred[tid + 128][i] + gred[tid + 192][i];
#pragma unroll
    for (int i = 25; i < 32; ++i) dst[i] = 0.f;
  }
}

// ---- k_forward: P[ciQ] = conv3x3 pad1(yp0[ciQ slice], WtF2) partials --------
// grid 512 = b(2) | oT(2) | ciQ(2) | band(3); block: 16 och x 4 rows x 32 cols,
// 8 steps over 32 ci. 2-och/thread + aligned b128 reads + 2 blocks/CU.
__global__ __launch_bounds__(256) void k_forward(const float* __restrict__ yp0,
                                                 const float* __restrict__ WtF2,
                                                 float* __restrict__ P) {
  __shared__ __align__(16) float wS[6144];    // [16 och][32 ci][12]
  __shared__ __align__(16) float sS[1920];
  int tid = threadIdx.x, blk = blockIdx.x;
  int b = blk >> 7, oT = (blk >> 5) & 3, ciQ = (blk >> 3) & 3, band = blk & 7;
  {
    const float4* src = (const float4*)(WtF2 + (size_t)(ciQ * 4 + oT) * 6144);
    float4* d4 = (float4*)wS;
    for (int i = tid; i < 1536; i += 256) d4[i] = src[i];
  }
  for (int i = tid; i < 1920; i += 256) sS[i] = 0.f;
  int wv = tid >> 6, lane = tid & 63;
  int srow = lane >> 3, scol = lane & 7;
  int gr = band * 4 - 1 + srow;
  bool sv = (srow < 6) && (gr >= 0) && (gr < 32);
  const float* sbase = yp0 + (size_t)(b * 128 + ciQ * 32 + wv) * 1024 + gr * 32 + scol * 4;
  float* sd0 = sS + wv * 240 + srow * 40 + 2 + scol * 4;
  int co2 = tid >> 5;
  int pg = tid & 31;
  int row_l = pg >> 3, c0 = (pg & 7) * 4;
  const float* w0p = wS + (size_t)(co2 * 2) * 384;
  const float* w1p = w0p + 384;
  float a0[4] = {0, 0, 0, 0}, a1[4] = {0, 0, 0, 0};
  float4 stg;
  if (sv) stg = *(const float4*)(sbase);
  __syncthreads();
  if (sv) stg_write(sd0, stg);
  __syncthreads();
  for (int st = 0; st < 8; st += 2) {
    if (sv) stg = *(const float4*)(sbase + (size_t)((st + 1) * 4) * 1024);
    conv3x2(sS, w0p, w1p, st * 4, row_l, c0, a0, a1);
    if (sv) stg_write(sd0 + 960, stg);
    __syncthreads();
    bool more = (st + 2 < 8);
    if (more && sv) stg = *(const float4*)(sbase + (size_t)((st + 2) * 4) * 1024);
    conv3x2(sS + 960, w0p, w1p, (st + 1) * 4, row_l, c0, a0, a1);
    if (more && sv) stg_write(sd0, stg);
    __syncthreads();
  }
  int gi = band * 4 + row_l;
  int och = oT * 16 + co2 * 2;
  size_t off = (size_t)ciQ * 262144 + (size_t)(b * 64 + och) * 1024 + gi * 32 + c0;
  float4 o0 = {a0[0], a0[1], a0[2], a0[3]};
  float4 o1 = {a1[0], a1[1], a1[2], a1[3]};
  *(float4*)(P + off) = o0;
  *(float4*)(P + off + 1024) = o1;
}

// ---- k_vsub: v0 = x - (P0+P1+P2+P3) -----------------------------------------
__global__ __launch_bounds__(256) void k_vsub(const float* __restrict__ x,
                                              const float* __restrict__ P,
                                              float* __restrict__ v0) {
  size_t i = (size_t)(blockIdx.x * 256 + threadIdx.x) * 4;
  float4 xv = *(const float4*)(x + i);
  float4 p0 = *(const float4*)(P + i);
  float4 p1 = *(const float4*)(P + 262144 + i);
  float4 p2 = *(const float4*)(P + 524288 + i);
  float4 p3 = *(const float4*)(P + 786432 + i);
  float4 r = {xv.x - p0.x - p1.x - p2.x - p3.x,
              xv.y - p0.y - p1.y - p2.y - p3.y,
              xv.z - p0.z - p1.z - p2.z - p3.z,
              xv.w - p0.w - p1.w - p2.w - p3.w};
  *(float4*)(v0 + i) = r;
}

// ---- k_applyG: v_{j+1} = G (*) v_j (5x5 pad2, 64->64ch) — round-3 version ---
__global__ __launch_bounds__(256) void k_applyG(const float* __restrict__ vin,
                                                float* __restrict__ vout,
                                                const float* __restrict__ G) {
  __shared__ __align__(16) float sIn[2][8 * 40];
  int tid = threadIdx.x;
  int blk = blockIdx.x;
  int b = blk >> 7, och_t = (blk >> 3) & 15, row_t = blk & 7;
  int wv = __builtin_amdgcn_readfirstlane(tid >> 6);
  int och = och_t * 4 + wv;
  int row_l = (tid >> 4) & 3;
  int cg = tid & 15;
  for (int i = tid; i < 2 * 320; i += 256) ((float*)sIn)[i] = 0.f;
  bool stager = ((tid & 3) == 0);
  int task = tid >> 2;
  int srow = task >> 3, scg = task & 7;
  int gr = row_t * 4 - 2 + srow;
  bool srv = stager && gr >= 0 && gr < 32;
  const float* rbase = vin + ((long)(b * 64) * 1024 + (long)gr * 32 + scg * 4);
  float* sdst = &sIn[0][srow * 40 + 4 + scg * 4];
  const float* gb = G + (size_t)och * 64 * 32;
  float wA[28], wB[28];
  float acc0 = 0.f, acc1 = 0.f;
  float4 stg;
  if (srv) stg = *(const float4*)(rbase);
  wload(gb, 0, wA);
  __syncthreads();
  if (srv) *(float4*)(sdst) = stg;
  __syncthreads();
  for (int o = 0; o < 64; o += 2) {
    if (srv) stg = *(const float4*)(rbase + (size_t)(o + 1) * 1024);
    wload(gb, o + 1, wB);
    conv5(sIn[0], row_l, cg, wA, acc0, acc1);
    if (srv) *(float4*)(sdst + 320) = stg;
    __syncthreads();
    bool more = (o + 2 < 64);
    if (more) {
      if (srv) stg = *(const float4*)(rbase + (size_t)(o + 2) * 1024);
      wload(gb, o + 2, wA);
    }
    conv5(sIn[1], row_l, cg, wB, acc0, acc1);
    if (more && srv) *(float4*)(sdst) = stg;
    __syncthreads();
  }
  int gi = row_t * 4 + row_l;
  size_t own = ((size_t)(b * 64 + och) * 32 + gi) * 32 + cg * 2;
  float2 ov = {acc0, acc1};
  *(float2*)(vout + own) = ov;
}

// ---- k_gamma ----------------------------------------------------------------
__global__ __launch_bounds__(256) void k_gamma(const float* __restrict__ V,
                                               float* __restrict__ Gam) {
  __shared__ float ws4[4];
  int tid = threadIdx.x;
  int p = blockIdx.x >> 3, slice = blockIdx.x & 7;
  int i = 0, rem = p;
  while (rem >= KRYLOV - i) { rem -= KRYLOV - i; ++i; }
  int j = i + rem;
  const float4* vi = (const float4*)(V + (size_t)i * VPLANE);
  const float4* vj = (const float4*)(V + (size_t)j * VPLANE);
  int base = slice * 8192;
  float acc = 0.f;
  for (int t = tid; t < 8192; t += 256) {
    float4 a = vi[base + t], c = vj[base + t];
    acc = fmaf(a.x, c.x, acc);
    acc = fmaf(a.y, c.y, acc);
    acc = fmaf(a.z, c.z, acc);
    acc = fmaf(a.w, c.w, acc);
  }
#pragma unroll
  for (int d = 32; d; d >>= 1) acc += __shfl_down(acc, d, 64);
  if ((tid & 63) == 0) ws4[tid >> 6] = acc;
  __syncthreads();
  if (tid == 0) {
    float tot = ws4[0] + ws4[1] + ws4[2] + ws4[3];
    atomicAdd(&Gam[i * KRYLOV + j], tot);
    if (i != j) atomicAdd(&Gam[j * KRYLOV + i], tot);
  }
}

// ---- k_scalar ---------------------------------------------------------------
__global__ __launch_bounds__(64) void k_scalar(const float* __restrict__ Gam,
                                               float* __restrict__ dvec) {
  float g00 = Gam[0], g01 = Gam[1], g02 = Gam[2];
  float g11 = Gam[4], g12 = Gam[5], g22 = Gam[8];
  float c0 = 1.f, c1 = 0.f, c2 = 0.f;
  float d0 = 0.f, d1 = 0.f, d2 = 0.f;
#pragma unroll
  for (int seg = 0; seg < 20; ++seg) {
    float pr = g00 * c0 * c0 + g11 * c1 * c1 + g22 * c2 * c2 +
               2.f * (g01 * c0 * c1 + g02 * c0 * c2 + g12 * c1 * c2);
    float a = LR_F * __builtin_amdgcn_rsqf(pr);
    float a2 = a * a, a3 = a2 * a;
    d0 += 25.f * a * c0;
    d1 += 25.f * a * c1 - 300.f * a2 * c0;
    d2 += 25.f * a * c2 - 300.f * a2 * c1 + 2300.f * a3 * c0;
    float t1 = c1 - 25.f * a * c0;
    float t2 = c2 - 25.f * a * c1 + 300.f * a2 * c0;
    c1 = t1; c2 = t2;
  }
  if (threadIdx.x == 0) { dvec[0] = d0; dvec[1] = d1; dvec[2] = d2; }
}

// ---- k_combine --------------------------------------------------------------
__global__ __launch_bounds__(256) void k_combine(float* __restrict__ V,
                                                 const float* __restrict__ dvec) {
  int idx = blockIdx.x * 256 + threadIdx.x;
  float d[KRYLOV];
#pragma unroll
  for (int i = 0; i < KRYLOV; ++i) d[i] = dvec[i];
  float4 acc = {0.f, 0.f, 0.f, 0.f};
#pragma unroll
  for (int i = 0; i < KRYLOV; ++i) {
    float4 v = *(const float4*)(V + (size_t)i * VPLANE + (size_t)idx * 4);
    acc.x = fmaf(d[i], v.x, acc.x);
    acc.y = fmaf(d[i], v.y, acc.y);
    acc.z = fmaf(d[i], v.z, acc.z);
    acc.w = fmaf(d[i], v.w, acc.w);
  }
  *(float4*)(V + (size_t)idx * 4) = acc;
}

// ---- k_finalize: out = yp0 + conv3x3 pad1(s, WFlip) + 1x1(x, Wb slot9) ------
__global__ __launch_bounds__(256) void k_finalize(const float* __restrict__ x,
                                                  const float* __restrict__ WFlip,
                                                  const float* __restrict__ yp0,
                                                  const float* __restrict__ s,
                                                  float* __restrict__ out) {
  __shared__ __align__(16) float wS[12288];   // [16 co][64 ci][12] (slot9=bypass)
  __shared__ __align__(16) float sS[1920];
  __shared__ __align__(16) float xS[1024];    // [2][4 pl][4*32]
  int tid = threadIdx.x, blk = blockIdx.x;
  int b = blk >> 6, coT = (blk >> 3) & 7, band = blk & 7;
  {
    const float4* src = (const float4*)(WFlip + (size_t)coT * 12288);
    float4* d4 = (float4*)wS;
    for (int i = tid; i < 3072; i += 256) d4[i] = src[i];
  }
  for (int i = tid; i < 1920; i += 256) sS[i] = 0.f;
  int wv = tid >> 6, lane = tid & 63;
  int srow = lane >> 3, scol = lane & 7;
  int gr = band * 4 - 1 + srow;
  bool sv = (srow < 6) && (gr >= 0) && (gr < 32);
  const float* sbase = s + (size_t)(b * 64 + wv) * 1024 + gr * 32 + scol * 4;
  float* sd0 = sS + wv * 240 + srow * 40 + 2 + scol * 4;
  bool xv = (lane >= 48);
  int sub = lane - 48;
  int xr0 = sub >> 3, xc0 = sub & 7;
  int xr1 = (sub + 16) >> 3, xc1 = (sub + 16) & 7;
  const float* xbase = x + (size_t)(b * 64 + wv) * 1024 + band * 4 * 32;
  float* xd0 = xS + wv * 128;
  int co2 = tid >> 5;
  int pg = tid & 31;
  int row_l = pg >> 3, c0 = (pg & 7) * 4;
  const float* w0p = wS + (size_t)(co2 * 2) * 768;
  const float* w1p = w0p + 768;
  float a0[4] = {0, 0, 0, 0}, a1[4] = {0, 0, 0, 0};
  float4 stg, sx0, sx1;
  if (sv) stg = *(const float4*)(sbase);
  if (xv) {
    sx0 = *(const float4*)(xbase + xr0 * 32 + xc0 * 4);
    sx1 = *(const float4*)(xbase + xr1 * 32 + xc1 * 4);
  }
  __syncthreads();
  if (sv) stg_write(sd0, stg);
  if (xv) {
    *(float4*)(xd0 + xr0 * 32 + xc0 * 4) = sx0;
    *(float4*)(xd0 + xr1 * 32 + xc1 * 4) = sx1;
  }
  __syncthreads();
  for (int st = 0; st < 16; st += 2) {
    size_t po1 = (size_t)((st + 1) * 4) * 1024;
    if (sv) stg = *(const float4*)(sbase + po1);
    if (xv) {
      sx0 = *(const float4*)(xbase + po1 + xr0 * 32 + xc0 * 4);
      sx1 = *(const float4*)(xbase + po1 + xr1 * 32 + xc1 * 4);
    }
    conv3x2(sS, w0p, w1p, st * 4, row_l, c0, a0, a1);
#pragma unroll
    for (int cl = 0; cl < 4; ++cl) {
      float wb0 = w0p[(size_t)(st * 4 + cl) * 12 + 9];
      float wb1 = w1p[(size_t)(st * 4 + cl) * 12 + 9];
      float4 xq = *(const float4*)(xS + cl * 128 + row_l * 32 + c0);
      float xf[4] = {xq.x, xq.y, xq.z, xq.w};
#pragma unroll
      for (int k = 0; k < 4; ++k) {
        a0[k] = fmaf(xf[k], wb0, a0[k]);
        a1[k] = fmaf(xf[k], wb1, a1[k]);
      }
    }
    if (sv) stg_write(sd0 + 960, stg);
    if (xv) {
      *(float4*)(xd0 + 512 + xr0 * 32 + xc0 * 4) = sx0;
      *(float4*)(xd0 + 512 + xr1 * 32 + xc1 * 4) = sx1;
    }
    __syncthreads();
    bool more = (st + 2 < 16);
    size_t po2 = (size_t)((st + 2) * 4) * 1024;
    if (more && sv) stg = *(const float4*)(sbase + po2);
    if (more && xv) {
      sx0 = *(const float4*)(xbase + po2 + xr0 * 32 + xc0 * 4);
      sx1 = *(const float4*)(xbase + po2 + xr1 * 32 + xc1 * 4);
    }
    conv3x2(sS + 960, w0p, w1p, (st + 1) * 4, row_l, c0, a0, a1);
#pragma unroll
    for (int cl = 0; cl < 4; ++cl) {
      float wb0 = w0p[(size_t)((st + 1) * 4 + cl) * 12 + 9];
      float wb1 = w1p[(size_t)((st + 1) * 4 + cl) * 12 + 9];
      float4 xq = *(const float4*)(xS + 512 + cl * 128 + row_l * 32 + c0);
      float xf[4] = {xq.x, xq.y, xq.z, xq.w};
#pragma unroll
      for (int k = 0; k < 4; ++k) {
        a0[k] = fmaf(xf[k], wb0, a0[k]);
        a1[k] = fmaf(xf[k], wb1, a1[k]);
      }
    }
    if (more && sv) stg_write(sd0, stg);
    if (more && xv) {
      *(float4*)(xd0 + xr0 * 32 + xc0 * 4) = sx0;
      *(float4*)(xd0 + xr1 * 32 + xc1 * 4) = sx1;
    }
    __syncthreads();
  }
  int gi = band * 4 + row_l;
  int co = coT * 16 + co2 * 2;
  size_t off0 = (size_t)(b * 128 + co) * 1024 + gi * 32 + c0;
  size_t off1 = off0 + 1024;
  float4 y0 = *(const float4*)(yp0 + off0);
  float4 y1 = *(const float4*)(yp0 + off1);
  float4 o0 = {a0[0] + y0.x, a0[1] + y0.y, a0[2] + y0.z, a0[3] + y0.w};
  float4 o1 = {a1[0] + y1.x, a1[1] + y1.y, a1[2] + y1.z, a1[3] + y1.w};
  *(float4*)(out + off0) = o0;
  *(float4*)(out + off1) = o1;
}

// ---- launch -----------------------------------------------------------------
extern "C" void kernel_launch(void* const* d_in, const int* in_sizes, int n_in,
                              void* d_out, int out_size, void* d_ws, size_t ws_size,
                              hipStream_t stream) {
  const float* x   = (const float*)d_in[0];
  const float* Wff = (const float*)d_in[1];
  const float* Wfb = (const float*)d_in[2];
  const float* Wb  = (const float*)d_in[3];
  float* out = (float*)d_out;

  float* yp0   = (float*)d_ws;                 // 524288
  float* V     = yp0 + 524288;                 // 3 * 262144
  float* G5    = V + (size_t)KRYLOV * VPLANE;  // 131072
  float* Gam   = G5 + 131072;                  // 16
  float* dvec  = Gam + 16;                     // 16
  float* WffP  = dvec + 16;                    // 98304
  float* WtF2  = WffP + 98304;                 // 98304
  float* WFlip = WtF2 + 98304;                 // 98304
  float* P     = WFlip + 98304;                // 4 * 262144

  hipLaunchKernelGGL(k_prep,    dim3(96),  dim3(256), 0, stream, Wff, Wfb, Wb, WffP, WtF2, WFlip);
  hipLaunchKernelGGL(k_init,    dim3(256), dim3(256), 0, stream, x, WffP, yp0);
  hipLaunchKernelGGL(k_gram,    dim3(64),  dim3(256), 0, stream, Wfb, G5, Gam);
  hipLaunchKernelGGL(k_forward, dim3(512), dim3(256), 0, stream, yp0, WtF2, P);
  hipLaunchKernelGGL(k_vsub,    dim3(256), dim3(256), 0, stream, x, P, V);
  for (int j = 0; j + 1 < KRYLOV; ++j) {
    hipLaunchKernelGGL(k_applyG, dim3(512), dim3(256), 0, stream,
                       V + (size_t)j * VPLANE, V + (size_t)(j + 1) * VPLANE, G5);
  }
  hipLaunchKernelGGL(k_gamma,   dim3(48),  dim3(256), 0, stream, V, Gam);
  hipLaunchKernelGGL(k_scalar,  dim3(1),   dim3(64),  0, stream, Gam, dvec);
  hipLaunchKernelGGL(k_combine, dim3(256), dim3(256), 0, stream, V, dvec);
  hipLaunchKernelGGL(k_finalize, dim3(256), dim3(256), 0, stream, x, WFlip, yp0, V, out);
}

// Round 9
// 244.856 us; speedup vs baseline: 6.5227x; 1.1978x over previous
//
#include <hip/hip_runtime.h>

#define NUM_ITERS 500
#define LR_F 0.001f
#define KRYLOV 3
#define VPLANE 262144    // 4*64*1024 floats per Krylov vector
// 500 = 20 segments * 25 steps; C(25,1)=25, C(25,2)=300, C(25,3)=2300

// ---- register-safe unpack helpers -------------------------------------------
__device__ __forceinline__ void ldw12(const float* __restrict__ wp, float w[12]) {
  float4 q0 = ((const float4*)wp)[0];
  float4 q1 = ((const float4*)wp)[1];
  float4 q2 = ((const float4*)wp)[2];
  w[0] = q0.x; w[1] = q0.y; w[2] = q0.z; w[3] = q0.w;
  w[4] = q1.x; w[5] = q1.y; w[6] = q1.z; w[7] = q1.w;
  w[8] = q2.x; w[9] = q2.y; w[10] = q2.z; w[11] = q2.w;
}

// aligned b128 pair: f[0..7] = LDS words rp..rp+7 (rp 4-word aligned)
__device__ __forceinline__ void ldrow8b(const float* __restrict__ rp, float f[8]) {
  float4 a = *(const float4*)(rp);
  float4 b = *(const float4*)(rp + 4);
  f[0] = a.x; f[1] = a.y; f[2] = a.z; f[3] = a.w;
  f[4] = b.x; f[5] = b.y; f[6] = b.z; f[7] = b.w;
}

// load 25 (padded 28) weights for row o from table base (stride 32, 16B aligned)
__device__ __forceinline__ void wload(const float* __restrict__ gb, int o, float w[28]) {
  const float4* g4 = (const float4*)(gb + o * 32);
#pragma unroll
  for (int i = 0; i < 7; ++i) {
    float4 v = g4[i];
    w[4 * i] = v.x; w[4 * i + 1] = v.y; w[4 * i + 2] = v.z; w[4 * i + 3] = v.w;
  }
}

// staging write helper: float4 -> LDS word addr == 2 (mod 4), as two float2
__device__ __forceinline__ void stg_write(float* sd, float4 v) {
  float2 u = {v.x, v.y}, w = {v.z, v.w};
  *(float2*)sd = u;
  *(float2*)(sd + 2) = w;
}

// ---- weight prep ------------------------------------------------------------
// table0: WtF2[ciQ(4)][oT(4)][o16(16)][ci32(32)][12]  (forward, transposed)
// table1: WffP[co*64+ci][12]      table2: WFlip (flipped 3x3 + bypass slot 9)
__global__ __launch_bounds__(256) void k_prep(const float* __restrict__ Wff,
                                              const float* __restrict__ Wfb,
                                              const float* __restrict__ Wb,
                                              float* __restrict__ WffP,
                                              float* __restrict__ WtF,
                                              float* __restrict__ WFlip) {
  int g = blockIdx.x * 256 + threadIdx.x;
  int table = g >> 13, t = g & 8191;
  float w[12];
#pragma unroll
  for (int k = 0; k < 12; ++k) w[k] = 0.f;
  float* dst;
  if (table == 0) {
    int o = t >> 7, c = t & 127;
    const float* src = Wfb + (size_t)(c * 64 + o) * 9;
#pragma unroll
    for (int k = 0; k < 9; ++k) w[k] = src[k];
    int ciQ = c >> 5, ci32 = c & 31, oT = o >> 4, o16 = o & 15;
    dst = WtF + ((size_t)(((ciQ * 4 + oT) * 16 + o16) * 32) + ci32) * 12;
  } else if (table == 1) {
    const float* src = Wff + (size_t)t * 9;
#pragma unroll
    for (int k = 0; k < 9; ++k) w[k] = src[k];
    dst = WffP + (size_t)t * 12;
  } else {
    const float* src = Wfb + (size_t)t * 9;
#pragma unroll
    for (int k = 0; k < 9; ++k) w[k] = src[8 - k];
    w[9] = Wb[t];
    dst = WFlip + (size_t)t * 12;
  }
  float4 v0 = {w[0], w[1], w[2], w[3]};
  float4 v1 = {w[4], w[5], w[6], w[7]};
  float4 v2 = {w[8], w[9], w[10], w[11]};
  ((float4*)dst)[0] = v0; ((float4*)dst)[1] = v1; ((float4*)dst)[2] = v2;
}

// ---- conv3x2 (3x3, 2 och, 4 px) ---------------------------------------------
__device__ __forceinline__ void conv3x2(const float* __restrict__ buf,   // 4 planes x 240
                                        const float* __restrict__ w0p,   // [ci][12]
                                        const float* __restrict__ w1p,
                                        int stci, int row_l, int c0,
                                        float a0[4], float a1[4]) {
#pragma unroll
  for (int cl = 0; cl < 4; ++cl) {
    float w0r[12], w1r[12];
    ldw12(w0p + (size_t)(stci + cl) * 12, w0r);
    ldw12(w1p + (size_t)(stci + cl) * 12, w1r);
    const float* pb = buf + cl * 240;
#pragma unroll
    for (int di = 0; di < 3; ++di) {
      float f[8];
      ldrow8b(pb + (row_l + di) * 40 + c0, f);
#pragma unroll
      for (int dj = 0; dj < 3; ++dj) {
        float wa = w0r[di * 3 + dj], wb = w1r[di * 3 + dj];
#pragma unroll
        for (int k = 0; k < 4; ++k) {
          a0[k] = fmaf(f[k + dj + 1], wa, a0[k]);
          a1[k] = fmaf(f[k + dj + 1], wb, a1[k]);
        }
      }
    }
  }
}

// ---- conv16: 5x5 over a full-plane LDS buffer (pitch 40, halo+2), 16 px -----
// out(R,C) = sum_{di,dj} w[di*5+dj] * in(R+di-2, C+dj-2); R=strip4+k, C=cg4+c
__device__ __forceinline__ void conv16(const float* __restrict__ pb, const float w[28],
                                       int strip4, int cg4, float acc[16]) {
#pragma unroll
  for (int r = 0; r < 8; ++r) {
    float f[8];
    ldrow8b(pb + (strip4 + r) * 40 + cg4, f);
#pragma unroll
    for (int k = 0; k < 4; ++k) {
      int di = r - k;
      if (di >= 0 && di < 5) {
#pragma unroll
        for (int dj = 0; dj < 5; ++dj) {
          float wv = w[di * 5 + dj];
#pragma unroll
          for (int c = 0; c < 4; ++c)
            acc[k * 4 + c] = fmaf(f[c + dj], wv, acc[k * 4 + c]);
        }
      }
    }
  }
}

// ---- k_init: yp0(32x32) = relu(conv3x3 pad1(x, Wff)) ------------------------
__global__ __launch_bounds__(256) void k_init(const float* __restrict__ x,
                                              const float* __restrict__ WffP,
                                              float* __restrict__ yp0) {
  __shared__ __align__(16) float wS[12288];   // [16 co][64 ci][12]
  __shared__ __align__(16) float sS[1920];    // [2][4 pl][6*40]
  int tid = threadIdx.x, blk = blockIdx.x;
  int b = blk >> 6, coT = (blk >> 3) & 7, band = blk & 7;
  {
    const float4* src = (const float4*)(WffP + (size_t)coT * 12288);
    float4* d4 = (float4*)wS;
    for (int i = tid; i < 3072; i += 256) d4[i] = src[i];
  }
  for (int i = tid; i < 1920; i += 256) sS[i] = 0.f;
  int wv = tid >> 6, lane = tid & 63;
  int srow = lane >> 3, scol = lane & 7;
  int gr = band * 4 - 1 + srow;
  bool sv = (srow < 6) && (gr >= 0) && (gr < 32);
  const float* sbase = x + (size_t)(b * 64 + wv) * 1024 + gr * 32 + scol * 4;
  float* sd0 = sS + wv * 240 + srow * 40 + 2 + scol * 4;
  int co2 = tid >> 5;
  int pg = tid & 31;
  int row_l = pg >> 3, c0 = (pg & 7) * 4;
  const float* w0p = wS + (size_t)(co2 * 2) * 768;
  const float* w1p = w0p + 768;
  float a0[4] = {0, 0, 0, 0}, a1[4] = {0, 0, 0, 0};
  float4 stg;
  if (sv) stg = *(const float4*)(sbase);
  __syncthreads();
  if (sv) stg_write(sd0, stg);
  __syncthreads();
  for (int st = 0; st < 16; st += 2) {
    if (sv) stg = *(const float4*)(sbase + (size_t)((st + 1) * 4) * 1024);
    conv3x2(sS, w0p, w1p, st * 4, row_l, c0, a0, a1);
    if (sv) stg_write(sd0 + 960, stg);
    __syncthreads();
    bool more = (st + 2 < 16);
    if (more && sv) stg = *(const float4*)(sbase + (size_t)((st + 2) * 4) * 1024);
    conv3x2(sS + 960, w0p, w1p, (st + 1) * 4, row_l, c0, a0, a1);
    if (more && sv) stg_write(sd0, stg);
    __syncthreads();
  }
  int gi = band * 4 + row_l;
  int co = coT * 16 + co2 * 2;
  float4 o0 = {a0[0] > 0.f ? a0[0] : 0.f, a0[1] > 0.f ? a0[1] : 0.f,
               a0[2] > 0.f ? a0[2] : 0.f, a0[3] > 0.f ? a0[3] : 0.f};
  float4 o1 = {a1[0] > 0.f ? a1[0] : 0.f, a1[1] > 0.f ? a1[1] : 0.f,
               a1[2] > 0.f ? a1[2] : 0.f, a1[3] > 0.f ? a1[3] : 0.f};
  *(float4*)(yp0 + (size_t)(b * 128 + co) * 1024 + gi * 32 + c0) = o0;
  *(float4*)(yp0 + (size_t)(b * 128 + co + 1) * 1024 + gi * 32 + c0) = o1;
}

// ---- k_gram: 5x5 Gram of Wfb ------------------------------------------------
__global__ __launch_bounds__(256) void k_gram(const float* __restrict__ Wfb,
                                              float* __restrict__ G,
                                              float* __restrict__ Gam) {
  __shared__ float wA[128 * 9];
  __shared__ float gred[256][25];
  int tid = threadIdx.x;
  int op = blockIdx.x;
  if (blockIdx.x == 0 && tid < 16) Gam[tid] = 0.f;
  for (int i = tid; i < 1152; i += 256) {
    int c = i / 9, k = i - c * 9;
    wA[i] = Wfb[(size_t)(c * 64 + op) * 9 + k];
  }
  __syncthreads();
  int o = tid & 63, part = tid >> 6;
  float g[25];
#pragma unroll
  for (int i = 0; i < 25; ++i) g[i] = 0.f;
  for (int c = part * 32; c < part * 32 + 32; ++c) {
    float b9[9];
#pragma unroll
    for (int k = 0; k < 9; ++k) b9[k] = Wfb[(size_t)(c * 64 + o) * 9 + k];
    const float* a9 = &wA[c * 9];
#pragma unroll
    for (int ei = 0; ei < 3; ++ei)
#pragma unroll
      for (int ej = 0; ej < 3; ++ej) {
        float av = a9[ei * 3 + ej];
#pragma unroll
        for (int di = 0; di < 3; ++di)
#pragma unroll
          for (int dj = 0; dj < 3; ++dj)
            g[(ei - di + 2) * 5 + (ej - dj + 2)] = fmaf(av, b9[di * 3 + dj],
                                                        g[(ei - di + 2) * 5 + (ej - dj + 2)]);
      }
  }
#pragma unroll
  for (int i = 0; i < 25; ++i) gred[tid][i] = g[i];
  __syncthreads();
  if (part == 0) {
    float* dst = G + ((size_t)op * 64 + o) * 32;
#pragma unroll
    for (int i = 0; i < 25; ++i)
      dst[i] = gred[tid][i] + gred[tid + 64][i] + gred[tid + 128][i] + gred[tid + 192][i];
#pragma unroll
    for (int i = 25; i < 32; ++i) dst[i] = 0.f;
  }
}

// ---- k_forward: P[ciQ] = conv3x3 pad1(yp0[ciQ slice], WtF2) partials --------
// P slots 0-1 in d_out (Pd), slots 2-3 in ws (Pw).
__global__ __launch_bounds__(256) void k_forward(const float* __restrict__ yp0,
                                                 const float* __restrict__ WtF2,
                                                 float* __restrict__ Pd,
                                                 float* __restrict__ Pw) {
  __shared__ __align__(16) float wS[6144];    // [16 och][32 ci][12]
  __shared__ __align__(16) float sS[1920];
  int tid = threadIdx.x, blk = blockIdx.x;
  int b = blk >> 7, oT = (blk >> 5) & 3, ciQ = (blk >> 3) & 3, band = blk & 7;
  {
    const float4* src = (const float4*)(WtF2 + (size_t)(ciQ * 4 + oT) * 6144);
    float4* d4 = (float4*)wS;
    for (int i = tid; i < 1536; i += 256) d4[i] = src[i];
  }
  for (int i = tid; i < 1920; i += 256) sS[i] = 0.f;
  int wv = tid >> 6, lane = tid & 63;
  int srow = lane >> 3, scol = lane & 7;
  int gr = band * 4 - 1 + srow;
  bool sv = (srow < 6) && (gr >= 0) && (gr < 32);
  const float* sbase = yp0 + (size_t)(b * 128 + ciQ * 32 + wv) * 1024 + gr * 32 + scol * 4;
  float* sd0 = sS + wv * 240 + srow * 40 + 2 + scol * 4;
  int co2 = tid >> 5;
  int pg = tid & 31;
  int row_l = pg >> 3, c0 = (pg & 7) * 4;
  const float* w0p = wS + (size_t)(co2 * 2) * 384;
  const float* w1p = w0p + 384;
  float a0[4] = {0, 0, 0, 0}, a1[4] = {0, 0, 0, 0};
  float4 stg;
  if (sv) stg = *(const float4*)(sbase);
  __syncthreads();
  if (sv) stg_write(sd0, stg);
  __syncthreads();
  for (int st = 0; st < 8; st += 2) {
    if (sv) stg = *(const float4*)(sbase + (size_t)((st + 1) * 4) * 1024);
    conv3x2(sS, w0p, w1p, st * 4, row_l, c0, a0, a1);
    if (sv) stg_write(sd0 + 960, stg);
    __syncthreads();
    bool more = (st + 2 < 8);
    if (more && sv) stg = *(const float4*)(sbase + (size_t)((st + 2) * 4) * 1024);
    conv3x2(sS + 960, w0p, w1p, (st + 1) * 4, row_l, c0, a0, a1);
    if (more && sv) stg_write(sd0, stg);
    __syncthreads();
  }
  int gi = band * 4 + row_l;
  int och = oT * 16 + co2 * 2;
  float* Pbase = (ciQ < 2) ? (Pd + (size_t)ciQ * 262144) : (Pw + (size_t)(ciQ - 2) * 262144);
  size_t off = (size_t)(b * 64 + och) * 1024 + gi * 32 + c0;
  float4 o0 = {a0[0], a0[1], a0[2], a0[3]};
  float4 o1 = {a1[0], a1[1], a1[2], a1[3]};
  *(float4*)(Pbase + off) = o0;
  *(float4*)(Pbase + off + 1024) = o1;
}

// ---- k_vsub: v0 = x - (P0+P1+P2+P3) -----------------------------------------
__global__ __launch_bounds__(256) void k_vsub(const float* __restrict__ x,
                                              const float* __restrict__ Pd,
                                              const float* __restrict__ Pw,
                                              float* __restrict__ v0) {
  size_t i = (size_t)(blockIdx.x * 256 + threadIdx.x) * 4;
  float4 xv = *(const float4*)(x + i);
  float4 p0 = *(const float4*)(Pd + i);
  float4 p1 = *(const float4*)(Pd + 262144 + i);
  float4 p2 = *(const float4*)(Pw + i);
  float4 p3 = *(const float4*)(Pw + 262144 + i);
  float4 r = {xv.x - p0.x - p1.x - p2.x - p3.x,
              xv.y - p0.y - p1.y - p2.y - p3.y,
              xv.z - p0.z - p1.z - p2.z - p3.z,
              xv.w - p0.w - p1.w - p2.w - p3.w};
  *(float4*)(v0 + i) = r;
}

// ---- k_applyGp: partial v_{j+1}[ciO] = G(*)v_j over 8-ci octant -------------
// grid 512 = b(2) | ochQ(4) | ciO(3). Block: 4 och (wave-uniform) x full plane,
// thread: 16 px (4 rows x 4 cols). Full 36x40 zero-halo plane double-buffered.
__global__ __launch_bounds__(256) void k_applyGp(const float* __restrict__ vin,
                                                 float* __restrict__ Pd,
                                                 float* __restrict__ Pw,
                                                 const float* __restrict__ G) {
  __shared__ __align__(16) float sS[2880];    // 2 x 36*40
  int tid = threadIdx.x, blk = blockIdx.x;
  int b = blk >> 7, ochQ = (blk >> 3) & 15, ciO = blk & 7;
  int wv = __builtin_amdgcn_readfirstlane(tid >> 6);
  int och = ochQ * 4 + wv;
  int strip4 = ((tid >> 3) & 7) * 4;
  int cg4 = (tid & 7) * 4;
  for (int i = tid; i < 2880; i += 256) sS[i] = 0.f;
  int srow = tid >> 3, scg = tid & 7;   // staging: 32 rows x 8 cg, 1 task/thread
  const float* sbase = vin + (size_t)(b * 64 + ciO * 8) * 1024 + srow * 32 + scg * 4;
  float* sd0 = sS + (srow + 2) * 40 + 2 + scg * 4;
  const float* gb = G + (size_t)och * 2048;
  float wA[28], wB[28];
  float acc[16];
#pragma unroll
  for (int i = 0; i < 16; ++i) acc[i] = 0.f;
  float4 stg = *(const float4*)(sbase);
  wload(gb, ciO * 8, wA);
  __syncthreads();
  stg_write(sd0, stg);
  __syncthreads();
  for (int ci = 0; ci < 8; ci += 2) {
    stg = *(const float4*)(sbase + (size_t)(ci + 1) * 1024);
    wload(gb, ciO * 8 + ci + 1, wB);
    conv16(sS, wA, strip4, cg4, acc);
    stg_write(sd0 + 1440, stg);
    __syncthreads();
    bool more = (ci + 2 < 8);
    if (more) {
      stg = *(const float4*)(sbase + (size_t)(ci + 2) * 1024);
      wload(gb, ciO * 8 + ci + 2, wA);
    }
    conv16(sS + 1440, wB, strip4, cg4, acc);
    if (more) stg_write(sd0, stg);
    __syncthreads();
  }
  float* Pbase = (ciO < 2) ? (Pd + (size_t)ciO * 262144) : (Pw + (size_t)(ciO - 2) * 262144);
  float* dst = Pbase + (size_t)(b * 64 + och) * 1024 + strip4 * 32 + cg4;
#pragma unroll
  for (int k = 0; k < 4; ++k) {
    float4 o = {acc[k * 4], acc[k * 4 + 1], acc[k * 4 + 2], acc[k * 4 + 3]};
    *(float4*)(dst + k * 32) = o;
  }
}

// ---- k_sum8: vout = sum of 8 partials ---------------------------------------
__global__ __launch_bounds__(256) void k_sum8(const float* __restrict__ Pd,
                                              const float* __restrict__ Pw,
                                              float* __restrict__ vout) {
  size_t i = (size_t)(blockIdx.x * 256 + threadIdx.x) * 4;
  float4 s = *(const float4*)(Pd + i);
  float4 p = *(const float4*)(Pd + 262144 + i);
  s.x += p.x; s.y += p.y; s.z += p.z; s.w += p.w;
#pragma unroll
  for (int o = 0; o < 6; ++o) {
    float4 q = *(const float4*)(Pw + (size_t)o * 262144 + i);
    s.x += q.x; s.y += q.y; s.z += q.z; s.w += q.w;
  }
  *(float4*)(vout + i) = s;
}

// ---- k_gamma ----------------------------------------------------------------
__global__ __launch_bounds__(256) void k_gamma(const float* __restrict__ V,
                                               float* __restrict__ Gam) {
  __shared__ float ws4[4];
  int tid = threadIdx.x;
  int p = blockIdx.x >> 3, slice = blockIdx.x & 7;
  int i = 0, rem = p;
  while (rem >= KRYLOV - i) { rem -= KRYLOV - i; ++i; }
  int j = i + rem;
  const float4* vi = (const float4*)(V + (size_t)i * VPLANE);
  const float4* vj = (const float4*)(V + (size_t)j * VPLANE);
  int base = slice * 8192;
  float acc = 0.f;
  for (int t = tid; t < 8192; t += 256) {
    float4 a = vi[base + t], c = vj[base + t];
    acc = fmaf(a.x, c.x, acc);
    acc = fmaf(a.y, c.y, acc);
    acc = fmaf(a.z, c.z, acc);
    acc = fmaf(a.w, c.w, acc);
  }
#pragma unroll
  for (int d = 32; d; d >>= 1) acc += __shfl_down(acc, d, 64);
  if ((tid & 63) == 0) ws4[tid >> 6] = acc;
  __syncthreads();
  if (tid == 0) {
    float tot = ws4[0] + ws4[1] + ws4[2] + ws4[3];
    atomicAdd(&Gam[i * KRYLOV + j], tot);
    if (i != j) atomicAdd(&Gam[j * KRYLOV + i], tot);
  }
}

// ---- k_scalar ---------------------------------------------------------------
__global__ __launch_bounds__(64) void k_scalar(const float* __restrict__ Gam,
                                               float* __restrict__ dvec) {
  float g00 = Gam[0], g01 = Gam[1], g02 = Gam[2];
  float g11 = Gam[4], g12 = Gam[5], g22 = Gam[8];
  float c0 = 1.f, c1 = 0.f, c2 = 0.f;
  float d0 = 0.f, d1 = 0.f, d2 = 0.f;
#pragma unroll
  for (int seg = 0; seg < 20; ++seg) {
    float pr = g00 * c0 * c0 + g11 * c1 * c1 + g22 * c2 * c2 +
               2.f * (g01 * c0 * c1 + g02 * c0 * c2 + g12 * c1 * c2);
    float a = LR_F * __builtin_amdgcn_rsqf(pr);
    float a2 = a * a, a3 = a2 * a;
    d0 += 25.f * a * c0;
    d1 += 25.f * a * c1 - 300.f * a2 * c0;
    d2 += 25.f * a * c2 - 300.f * a2 * c1 + 2300.f * a3 * c0;
    float t1 = c1 - 25.f * a * c0;
    float t2 = c2 - 25.f * a * c1 + 300.f * a2 * c0;
    c1 = t1; c2 = t2;
  }
  if (threadIdx.x == 0) { dvec[0] = d0; dvec[1] = d1; dvec[2] = d2; }
}

// ---- k_combine --------------------------------------------------------------
__global__ __launch_bounds__(256) void k_combine(float* __restrict__ V,
                                                 const float* __restrict__ dvec) {
  int idx = blockIdx.x * 256 + threadIdx.x;
  float d[KRYLOV];
#pragma unroll
  for (int i = 0; i < KRYLOV; ++i) d[i] = dvec[i];
  float4 acc = {0.f, 0.f, 0.f, 0.f};
#pragma unroll
  for (int i = 0; i < KRYLOV; ++i) {
    float4 v = *(const float4*)(V + (size_t)i * VPLANE + (size_t)idx * 4);
    acc.x = fmaf(d[i], v.x, acc.x);
    acc.y = fmaf(d[i], v.y, acc.y);
    acc.z = fmaf(d[i], v.z, acc.z);
    acc.w = fmaf(d[i], v.w, acc.w);
  }
  *(float4*)(V + (size_t)idx * 4) = acc;
}

// ---- k_finalize: out = yp0 + conv3x3 pad1(s, WFlip) + 1x1(x, Wb slot9) ------
__global__ __launch_bounds__(256) void k_finalize(const float* __restrict__ x,
                                                  const float* __restrict__ WFlip,
                                                  const float* __restrict__ yp0,
                                                  const float* __restrict__ s,
                                                  float* __restrict__ out) {
  __shared__ __align__(16) float wS[12288];   // [16 co][64 ci][12] (slot9=bypass)
  __shared__ __align__(16) float sS[1920];
  __shared__ __align__(16) float xS[1024];    // [2][4 pl][4*32]
  int tid = threadIdx.x, blk = blockIdx.x;
  int b = blk >> 6, coT = (blk >> 3) & 7, band = blk & 7;
  {
    const float4* src = (const float4*)(WFlip + (size_t)coT * 12288);
    float4* d4 = (float4*)wS;
    for (int i = tid; i < 3072; i += 256) d4[i] = src[i];
  }
  for (int i = tid; i < 1920; i += 256) sS[i] = 0.f;
  int wv = tid >> 6, lane = tid & 63;
  int srow = lane >> 3, scol = lane & 7;
  int gr = band * 4 - 1 + srow;
  bool sv = (srow < 6) && (gr >= 0) && (gr < 32);
  const float* sbase = s + (size_t)(b * 64 + wv) * 1024 + gr * 32 + scol * 4;
  float* sd0 = sS + wv * 240 + srow * 40 + 2 + scol * 4;
  bool xv = (lane >= 48);
  int sub = lane - 48;
  int xr0 = sub >> 3, xc0 = sub & 7;
  int xr1 = (sub + 16) >> 3, xc1 = (sub + 16) & 7;
  const float* xbase = x + (size_t)(b * 64 + wv) * 1024 + band * 4 * 32;
  float* xd0 = xS + wv * 128;
  int co2 = tid >> 5;
  int pg = tid & 31;
  int row_l = pg >> 3, c0 = (pg & 7) * 4;
  const float* w0p = wS + (size_t)(co2 * 2) * 768;
  const float* w1p = w0p + 768;
  float a0[4] = {0, 0, 0, 0}, a1[4] = {0, 0, 0, 0};
  float4 stg, sx0, sx1;
  if (sv) stg = *(const float4*)(sbase);
  if (xv) {
    sx0 = *(const float4*)(xbase + xr0 * 32 + xc0 * 4);
    sx1 = *(const float4*)(xbase + xr1 * 32 + xc1 * 4);
  }
  __syncthreads();
  if (sv) stg_write(sd0, stg);
  if (xv) {
    *(float4*)(xd0 + xr0 * 32 + xc0 * 4) = sx0;
    *(float4*)(xd0 + xr1 * 32 + xc1 * 4) = sx1;
  }
  __syncthreads();
  for (int st = 0; st < 16; st += 2) {
    size_t po1 = (size_t)((st + 1) * 4) * 1024;
    if (sv) stg = *(const float4*)(sbase + po1);
    if (xv) {
      sx0 = *(const float4*)(xbase + po1 + xr0 * 32 + xc0 * 4);
      sx1 = *(const float4*)(xbase + po1 + xr1 * 32 + xc1 * 4);
    }
    conv3x2(sS, w0p, w1p, st * 4, row_l, c0, a0, a1);
#pragma unroll
    for (int cl = 0; cl < 4; ++cl) {
      float wb0 = w0p[(size_t)(st * 4 + cl) * 12 + 9];
      float wb1 = w1p[(size_t)(st * 4 + cl) * 12 + 9];
      float4 xq = *(const float4*)(xS + cl * 128 + row_l * 32 + c0);
      float xf[4] = {xq.x, xq.y, xq.z, xq.w};
#pragma unroll
      for (int k = 0; k < 4; ++k) {
        a0[k] = fmaf(xf[k], wb0, a0[k]);
        a1[k] = fmaf(xf[k], wb1, a1[k]);
      }
    }
    if (sv) stg_write(sd0 + 960, stg);
    if (xv) {
      *(float4*)(xd0 + 512 + xr0 * 32 + xc0 * 4) = sx0;
      *(float4*)(xd0 + 512 + xr1 * 32 + xc1 * 4) = sx1;
    }
    __syncthreads();
    bool more = (st + 2 < 16);
    size_t po2 = (size_t)((st + 2) * 4) * 1024;
    if (more && sv) stg = *(const float4*)(sbase + po2);
    if (more && xv) {
      sx0 = *(const float4*)(xbase + po2 + xr0 * 32 + xc0 * 4);
      sx1 = *(const float4*)(xbase + po2 + xr1 * 32 + xc1 * 4);
    }
    conv3x2(sS + 960, w0p, w1p, (st + 1) * 4, row_l, c0, a0, a1);
#pragma unroll
    for (int cl = 0; cl < 4; ++cl) {
      float wb0 = w0p[(size_t)((st + 1) * 4 + cl) * 12 + 9];
      float wb1 = w1p[(size_t)((st + 1) * 4 + cl) * 12 + 9];
      float4 xq = *(const float4*)(xS + 512 + cl * 128 + row_l * 32 + c0);
      float xf[4] = {xq.x, xq.y, xq.z, xq.w};
#pragma unroll
      for (int k = 0; k < 4; ++k) {
        a0[k] = fmaf(xf[k], wb0, a0[k]);
        a1[k] = fmaf(xf[k], wb1, a1[k]);
      }
    }
    if (more && sv) stg_write(sd0, stg);
    if (more && xv) {
      *(float4*)(xd0 + xr0 * 32 + xc0 * 4) = sx0;
      *(float4*)(xd0 + xr1 * 32 + xc1 * 4) = sx1;
    }
    __syncthreads();
  }
  int gi = band * 4 + row_l;
  int co = coT * 16 + co2 * 2;
  size_t off0 = (size_t)(b * 128 + co) * 1024 + gi * 32 + c0;
  size_t off1 = off0 + 1024;
  float4 y0 = *(const float4*)(yp0 + off0);
  float4 y1 = *(const float4*)(yp0 + off1);
  float4 o0 = {a0[0] + y0.x, a0[1] + y0.y, a0[2] + y0.z, a0[3] + y0.w};
  float4 o1 = {a1[0] + y1.x, a1[1] + y1.y, a1[2] + y1.z, a1[3] + y1.w};
  *(float4*)(out + off0) = o0;
  *(float4*)(out + off1) = o1;
}

// ---- launch -----------------------------------------------------------------
extern "C" void kernel_launch(void* const* d_in, const int* in_sizes, int n_in,
                              void* d_out, int out_size, void* d_ws, size_t ws_size,
                              hipStream_t stream) {
  const float* x   = (const float*)d_in[0];
  const float* Wff = (const float*)d_in[1];
  const float* Wfb = (const float*)d_in[2];
  const float* Wb  = (const float*)d_in[3];
  float* out = (float*)d_out;

  // ws layout (floats): yp0 524288 | V 3*262144 | G5 131072 | Gam 16 | dvec 16
  //                     | WFlip 98304 | Pw 6*262144 (slots 2-7; WffP/WtF2
  //                       overlay Pw slots 2-3 region, dead before applies)
  float* yp0   = (float*)d_ws;
  float* V     = yp0 + 524288;
  float* G5    = V + (size_t)KRYLOV * VPLANE;
  float* Gam   = G5 + 131072;
  float* dvec  = Gam + 16;
  float* WFlip = dvec + 16;
  float* Pw    = WFlip + 98304;
  float* WffP  = Pw + (size_t)2 * 262144;      // P slots 4-5 region (early use)
  float* WtF2  = WffP + 98304;
  float* Pd    = out;                           // P slots 0-1 in d_out scratch

  hipLaunchKernelGGL(k_prep,    dim3(96),  dim3(256), 0, stream, Wff, Wfb, Wb, WffP, WtF2, WFlip);
  hipLaunchKernelGGL(k_init,    dim3(256), dim3(256), 0, stream, x, WffP, yp0);
  hipLaunchKernelGGL(k_gram,    dim3(64),  dim3(256), 0, stream, Wfb, G5, Gam);
  hipLaunchKernelGGL(k_forward, dim3(512), dim3(256), 0, stream, yp0, WtF2, Pd, Pw);
  hipLaunchKernelGGL(k_vsub,    dim3(256), dim3(256), 0, stream, x, Pd, Pw, V);
  hipLaunchKernelGGL(k_applyGp, dim3(512), dim3(256), 0, stream, V, Pd, Pw, G5);
  hipLaunchKernelGGL(k_sum8,    dim3(256), dim3(256), 0, stream, Pd, Pw, V + VPLANE);
  hipLaunchKernelGGL(k_applyGp, dim3(512), dim3(256), 0, stream, V + VPLANE, Pd, Pw, G5);
  hipLaunchKernelGGL(k_sum8,    dim3(256), dim3(256), 0, stream, Pd, Pw, V + 2 * VPLANE);
  hipLaunchKernelGGL(k_gamma,   dim3(48),  dim3(256), 0, stream, V, Gam);
  hipLaunchKernelGGL(k_scalar,  dim3(1),   dim3(64),  0, stream, Gam, dvec);
  hipLaunchKernelGGL(k_combine, dim3(256), dim3(256), 0, stream, V, dvec);
  hipLaunchKernelGGL(k_finalize, dim3(256), dim3(256), 0, stream, x, WFlip, yp0, V, out);
}